// Round 1
// baseline (5025.951 us; speedup 1.0000x reference)
//
#include <hip/hip_runtime.h>

static __device__ __forceinline__ float sgn(float v) {
    return (v > 0.f) ? 1.f : ((v < 0.f) ? -1.f : 0.f);
}

// Fused: 3x3 conv (binary weights, pad 1, stride 1) + bias + relu + 2x2 maxpool.
// One thread per pooled output pixel. Block: 256 threads over pooled pixels.
// grid = (ceil(PH*PW/256), Cout, B)
template <int CIN>
__global__ void conv_pool_kernel(const float* __restrict__ x,   // [B, CIN, H, W]
                                 const float* __restrict__ w,   // [Cout, CIN, 3, 3]
                                 const float* __restrict__ bias,
                                 float* __restrict__ out,       // [B, Cout, H/2, W/2]
                                 int H, int W, int Cout) {
    const int PH = H >> 1, PW = W >> 1, P = PH * PW;
    const int co = blockIdx.y;
    const int b  = blockIdx.z;

    __shared__ float wl[CIN * 9];
    for (int i = threadIdx.x; i < CIN * 9; i += blockDim.x)
        wl[i] = sgn(w[co * CIN * 9 + i]);
    __syncthreads();

    const int p = blockIdx.x * blockDim.x + threadIdx.x;
    if (p >= P) return;
    const int py = p / PW, px = p % PW;
    const int y0 = 2 * py - 1, x0 = 2 * px - 1;

    float acc00 = 0.f, acc01 = 0.f, acc10 = 0.f, acc11 = 0.f;
    const float* xb = x + ((size_t)b * CIN) * H * W;

    for (int ci = 0; ci < CIN; ++ci) {
        const float* xc = xb + (size_t)ci * H * W;
        float in[4][4];
#pragma unroll
        for (int dy = 0; dy < 4; ++dy) {
            const int iy = y0 + dy;
            const bool yok = ((unsigned)iy < (unsigned)H);
#pragma unroll
            for (int dx = 0; dx < 4; ++dx) {
                const int ix = x0 + dx;
                in[dy][dx] = (yok && ((unsigned)ix < (unsigned)W))
                                 ? xc[iy * W + ix] : 0.f;
            }
        }
        const float* wc = &wl[ci * 9];
#pragma unroll
        for (int ky = 0; ky < 3; ++ky) {
#pragma unroll
            for (int kx = 0; kx < 3; ++kx) {
                const float wv = wc[ky * 3 + kx];
                acc00 = fmaf(wv, in[ky][kx],         acc00);
                acc01 = fmaf(wv, in[ky][kx + 1],     acc01);
                acc10 = fmaf(wv, in[ky + 1][kx],     acc10);
                acc11 = fmaf(wv, in[ky + 1][kx + 1], acc11);
            }
        }
    }
    // relu(maxpool(conv + b)) == max(relu(acc_i + b)) == relu(max(acc_i) + b)
    float m = fmaxf(fmaxf(acc00, acc01), fmaxf(acc10, acc11));
    out[(((size_t)b * Cout + co) * PH + py) * PW + px] = fmaxf(m + bias[co], 0.f);
}

// FC1: out[b,co] = relu(sum_k act[b,k] * sgn(wf[co,k]) + bf[co])
// One 64-lane wave per output element (128x128 outputs, K=50176).
__global__ void fc1_kernel(const float* __restrict__ act, // [128, 50176]
                           const float* __restrict__ wf,  // [128, 50176]
                           const float* __restrict__ bf,  // [128]
                           float* __restrict__ out) {     // [128, 128]
    const int K = 50176;
    const int wid  = blockIdx.x * (blockDim.x >> 6) + (threadIdx.x >> 6);
    const int lane = threadIdx.x & 63;
    const int b = wid >> 7, co = wid & 127;
    const float* a  = act + (size_t)b * K;
    const float* wr = wf  + (size_t)co * K;
    float acc = 0.f;
    for (int k = lane; k < K; k += 64)
        acc = fmaf(a[k], sgn(wr[k]), acc);
#pragma unroll
    for (int off = 32; off; off >>= 1)
        acc += __shfl_down(acc, off, 64);
    if (lane == 0) out[b * 128 + co] = fmaxf(acc + bf[co], 0.f);
}

// FC2: out[b,co] = sum_k act[b,k] * sgn(wf[co,k]) + bf[co]
// One thread per output element (128x1000 outputs, K=128).
__global__ void fc2_kernel(const float* __restrict__ act, // [128, 128]
                           const float* __restrict__ wf,  // [1000, 128]
                           const float* __restrict__ bf,  // [1000]
                           float* __restrict__ out) {     // [128, 1000]
    const int o = blockIdx.x * blockDim.x + threadIdx.x;
    if (o >= 128 * 1000) return;
    const int b = o / 1000, co = o % 1000;
    const float* a  = act + b * 128;
    const float* wr = wf + co * 128;
    float acc = 0.f;
#pragma unroll 8
    for (int k = 0; k < 128; ++k)
        acc = fmaf(a[k], sgn(wr[k]), acc);
    out[o] = acc + bf[co];
}

extern "C" void kernel_launch(void* const* d_in, const int* in_sizes, int n_in,
                              void* d_out, int out_size, void* d_ws, size_t ws_size,
                              hipStream_t stream) {
    const float* x   = (const float*)d_in[0];
    const float* w1  = (const float*)d_in[1];
    const float* b1  = (const float*)d_in[2];
    const float* w2  = (const float*)d_in[3];
    const float* b2  = (const float*)d_in[4];
    const float* w3  = (const float*)d_in[5];
    const float* b3  = (const float*)d_in[6];
    const float* wf1 = (const float*)d_in[7];
    const float* bf1 = (const float*)d_in[8];
    const float* wf2 = (const float*)d_in[9];
    const float* bf2 = (const float*)d_in[10];

    // Workspace layout (fp32), with reuse:
    //   h1: [128,16,112,112] = 102,760,448 B at offset 0
    //   h2: [128,32, 56, 56] =  51,380,224 B at offset 102,760,448
    //   h3: [128,64, 28, 28] =  25,690,112 B reuses h1's region
    //   f1: [128,128]        =      65,536 B reuses h2's region
    float* h1 = (float*)d_ws;
    float* h2 = (float*)((char*)d_ws + 102760448u);
    float* h3 = h1;
    float* f1 = h2;

    // conv1: [128,3,224,224] -> [128,16,112,112]; P = 112*112 = 12544
    conv_pool_kernel<3><<<dim3(49, 16, 128), 256, 0, stream>>>(x, w1, b1, h1, 224, 224, 16);
    // conv2: -> [128,32,56,56]; P = 3136
    conv_pool_kernel<16><<<dim3(13, 32, 128), 256, 0, stream>>>(h1, w2, b2, h2, 112, 112, 32);
    // conv3: -> [128,64,28,28]; P = 784
    conv_pool_kernel<32><<<dim3(4, 64, 128), 256, 0, stream>>>(h2, w3, b3, h3, 56, 56, 64);
    // fc1: [128,50176] x [128,50176]^T -> [128,128]; 16384 waves, 4 waves/block
    fc1_kernel<<<4096, 256, 0, stream>>>(h3, wf1, bf1, f1);
    // fc2: [128,128] x [1000,128]^T -> [128,1000]
    fc2_kernel<<<(128000 + 255) / 256, 256, 0, stream>>>(f1, wf2, bf2, (float*)d_out);
}

// Round 3
// 597.843 us; speedup vs baseline: 8.4068x; 8.4068x over previous
//
#include <hip/hip_runtime.h>

static __device__ __forceinline__ float sgn(float v) {
    return (v > 0.f) ? 1.f : ((v < 0.f) ? -1.f : 0.f);
}

// Fused: 3x3 conv (binary weights, pad 1, stride 1) + bias + relu + 2x2 maxpool.
// Each thread: NCO output channels x 2 pooled pixels (adjacent in x) from one
// in[4][6] register patch. Block 256 threads over pixel-pairs.
// grid = (ceil(PH*(PW/2)/256), Cout/NCO, B)
template <int CIN, int NCO>
__global__ void conv_pool_kernel(const float* __restrict__ x,   // [B, CIN, H, W]
                                 const float* __restrict__ w,   // [Cout, CIN, 3, 3]
                                 const float* __restrict__ bias,
                                 float* __restrict__ out,       // [B, Cout, H/2, W/2]
                                 int H, int W, int Cout) {
    const int PH = H >> 1, PW = W >> 1, PWH = PW >> 1;
    const int P2 = PH * PWH;
    const int cog = blockIdx.y * NCO;
    const int b   = blockIdx.z;

    __shared__ __align__(16) float wl[NCO][CIN][12];
    for (int i = threadIdx.x; i < NCO * CIN * 9; i += 256) {
        const int co = i / (CIN * 9), rem = i % (CIN * 9);
        wl[co][rem / 9][rem % 9] = sgn(w[(size_t)(cog + co) * CIN * 9 + rem]);
    }
    __syncthreads();

    const int p2 = blockIdx.x * 256 + threadIdx.x;
    if (p2 >= P2) return;
    const int py = p2 / PWH, px2 = p2 % PWH;
    const int y0 = 2 * py - 1;        // 4 input rows y0..y0+3
    const int x0 = 4 * px2 - 1;       // 6 input cols x0..x0+5

    // FIX (round 2 bug): must also exclude the bottom edge (y0+3 == H needs padding)
    const bool interior = (y0 >= 0) && (y0 + 3 < H) && (x0 >= 0) && (x0 + 5 < W);

    float acc[NCO][8];
#pragma unroll
    for (int c = 0; c < NCO; ++c)
#pragma unroll
        for (int q = 0; q < 8; ++q) acc[c][q] = 0.f;

    const float* xb = x + ((size_t)b * CIN) * H * W;

    for (int ci = 0; ci < CIN; ++ci) {
        const float* xc = xb + (size_t)ci * H * W;
        float in[4][6];
        if (interior) {
#pragma unroll
            for (int r = 0; r < 4; ++r) {
                const float* row = xc + (size_t)(y0 + r) * W + x0;
                in[r][0] = row[0];
                const float4 m = *(const float4*)(row + 1);  // 16B-aligned
                in[r][1] = m.x; in[r][2] = m.y; in[r][3] = m.z; in[r][4] = m.w;
                in[r][5] = row[5];
            }
        } else {
#pragma unroll
            for (int r = 0; r < 4; ++r) {
                const int iy = y0 + r;
                const bool yok = ((unsigned)iy < (unsigned)H);
#pragma unroll
                for (int c = 0; c < 6; ++c) {
                    const int ix = x0 + c;
                    in[r][c] = (yok && ((unsigned)ix < (unsigned)W))
                                   ? xc[(size_t)iy * W + ix] : 0.f;
                }
            }
        }
#pragma unroll
        for (int co = 0; co < NCO; ++co) {
            const float4* w4 = (const float4*)wl[co][ci];
            const float4 wA = w4[0], wB = w4[1], wC = w4[2];
            const float wv[9] = {wA.x, wA.y, wA.z, wA.w, wB.x, wB.y, wB.z, wB.w, wC.x};
#pragma unroll
            for (int ky = 0; ky < 3; ++ky)
#pragma unroll
                for (int kx = 0; kx < 3; ++kx) {
                    const float wgt = wv[ky * 3 + kx];
#pragma unroll
                    for (int u = 0; u < 2; ++u)
#pragma unroll
                        for (int sy = 0; sy < 2; ++sy)
#pragma unroll
                            for (int sx = 0; sx < 2; ++sx)
                                acc[co][u * 4 + sy * 2 + sx] =
                                    fmaf(wgt, in[sy + ky][2 * u + sx + kx],
                                         acc[co][u * 4 + sy * 2 + sx]);
                }
        }
    }

#pragma unroll
    for (int co = 0; co < NCO; ++co) {
        const float bv = bias[cog + co];
        float2 o;
        o.x = fmaxf(fmaxf(fmaxf(acc[co][0], acc[co][1]), fmaxf(acc[co][2], acc[co][3])) + bv, 0.f);
        o.y = fmaxf(fmaxf(fmaxf(acc[co][4], acc[co][5]), fmaxf(acc[co][6], acc[co][7])) + bv, 0.f);
        *(float2*)&out[(((size_t)b * Cout + cog + co) * PH + py) * PW + 2 * px2] = o;
    }
}

// FC1 stage A: split-K tiled GEMM. partial[ks][b][co] = sum_k act[b,k]*sgn(wf[co,k])
// Block: 256 threads (16x16), thread tile 2x2 (strided +16), block tile 32b x 32co.
// grid = (4 btiles, 4 ctiles, 16 ksplits). K per split = 3136, chunk = 64.
__global__ void fc1_stageA(const float* __restrict__ act, // [128, 50176]
                           const float* __restrict__ wf,  // [128, 50176]
                           float* __restrict__ partials) {// [16][128][128]
    const int K = 50176, KSPLIT = 3136, KC = 64;
    const int bt = blockIdx.x * 32, ct = blockIdx.y * 32, ks = blockIdx.z;
    const int tx = threadIdx.x & 15, ty = threadIdx.x >> 4;

    __shared__ __align__(16) float A[32][68];
    __shared__ __align__(16) float Wl[32][68];

    float a00 = 0.f, a01 = 0.f, a10 = 0.f, a11 = 0.f;

    const int k_base = ks * KSPLIT;
    for (int k0 = k_base; k0 < k_base + KSPLIT; k0 += KC) {
        __syncthreads();
#pragma unroll
        for (int j = 0; j < 2; ++j) {
            const int s = threadIdx.x + j * 256;   // 0..511
            const int r = s >> 4, c4 = (s & 15) * 4;
            const float4 av = *(const float4*)&act[(size_t)(bt + r) * K + k0 + c4];
            *(float4*)&A[r][c4] = av;
            float4 wv = *(const float4*)&wf[(size_t)(ct + r) * K + k0 + c4];
            wv.x = sgn(wv.x); wv.y = sgn(wv.y); wv.z = sgn(wv.z); wv.w = sgn(wv.w);
            *(float4*)&Wl[r][c4] = wv;
        }
        __syncthreads();
#pragma unroll
        for (int k4 = 0; k4 < 16; ++k4) {
            const float4 x0 = *(const float4*)&A[ty][k4 * 4];
            const float4 x1 = *(const float4*)&A[ty + 16][k4 * 4];
            const float4 w0 = *(const float4*)&Wl[tx][k4 * 4];
            const float4 w1 = *(const float4*)&Wl[tx + 16][k4 * 4];
            a00 = fmaf(x0.x, w0.x, fmaf(x0.y, w0.y, fmaf(x0.z, w0.z, fmaf(x0.w, w0.w, a00))));
            a01 = fmaf(x0.x, w1.x, fmaf(x0.y, w1.y, fmaf(x0.z, w1.z, fmaf(x0.w, w1.w, a01))));
            a10 = fmaf(x1.x, w0.x, fmaf(x1.y, w0.y, fmaf(x1.z, w0.z, fmaf(x1.w, w0.w, a10))));
            a11 = fmaf(x1.x, w1.x, fmaf(x1.y, w1.y, fmaf(x1.z, w1.z, fmaf(x1.w, w1.w, a11))));
        }
    }
    float* pb = partials + (size_t)ks * 128 * 128;
    pb[(bt + ty)      * 128 + ct + tx]      = a00;
    pb[(bt + ty)      * 128 + ct + tx + 16] = a01;
    pb[(bt + ty + 16) * 128 + ct + tx]      = a10;
    pb[(bt + ty + 16) * 128 + ct + tx + 16] = a11;
}

// FC1 stage B: reduce 16 partials + bias + relu -> f1[128][128]
__global__ void fc1_stageB(const float* __restrict__ partials,
                           const float* __restrict__ bf,
                           float* __restrict__ f1) {
    const int o = blockIdx.x * 256 + threadIdx.x;  // 0..16383
    float acc = 0.f;
#pragma unroll
    for (int ks = 0; ks < 16; ++ks) acc += partials[(size_t)ks * 16384 + o];
    f1[o] = fmaxf(acc + bf[o & 127], 0.f);
}

// FC2: out[b,co] = sum_k f1[b,k] * sgn(wf2[co,k]) + bf2[co]
__global__ void fc2_kernel(const float* __restrict__ act, // [128, 128]
                           const float* __restrict__ wf,  // [1000, 128]
                           const float* __restrict__ bf,
                           float* __restrict__ out) {     // [128, 1000]
    const int o = blockIdx.x * 256 + threadIdx.x;
    if (o >= 128 * 1000) return;
    const int b = o / 1000, co = o % 1000;
    const float* a  = act + b * 128;
    const float* wr = wf + co * 128;
    float acc = 0.f;
#pragma unroll 8
    for (int k = 0; k < 128; ++k)
        acc = fmaf(a[k], sgn(wr[k]), acc);
    out[o] = acc + bf[co];
}

extern "C" void kernel_launch(void* const* d_in, const int* in_sizes, int n_in,
                              void* d_out, int out_size, void* d_ws, size_t ws_size,
                              hipStream_t stream) {
    const float* x   = (const float*)d_in[0];
    const float* w1  = (const float*)d_in[1];
    const float* b1  = (const float*)d_in[2];
    const float* w2  = (const float*)d_in[3];
    const float* b2  = (const float*)d_in[4];
    const float* w3  = (const float*)d_in[5];
    const float* b3  = (const float*)d_in[6];
    const float* wf1 = (const float*)d_in[7];
    const float* bf1 = (const float*)d_in[8];
    const float* wf2 = (const float*)d_in[9];
    const float* bf2 = (const float*)d_in[10];

    // ws layout (fp32):
    //   h1: [128,16,112,112] 102,760,448 B @ 0          (dead after conv2)
    //   h2: [128,32,56,56]    51,380,224 B @ 102,760,448 (dead after conv3)
    //   h3: [128,64,28,28]    25,690,112 B @ 0 (reuses h1; read by fc1A)
    //   partials: 16*128*128*4 = 1 MB @ 33,554,432 (inside dead h1 tail)
    //   f1: [128,128] @ 102,760,448 (reuses dead h2)
    float* h1 = (float*)d_ws;
    float* h2 = (float*)((char*)d_ws + 102760448u);
    float* h3 = h1;
    float* pa = (float*)((char*)d_ws + 33554432u);
    float* f1 = h2;

    // conv1: 224x224 -> pooled 112x112; P2 = 112*56 = 6272
    conv_pool_kernel<3, 8><<<dim3(25, 2, 128), 256, 0, stream>>>(x, w1, b1, h1, 224, 224, 16);
    // conv2: 112x112 -> 56x56; P2 = 56*28 = 1568
    conv_pool_kernel<16, 8><<<dim3(7, 4, 128), 256, 0, stream>>>(h1, w2, b2, h2, 112, 112, 32);
    // conv3: 56x56 -> 28x28; P2 = 28*14 = 392
    conv_pool_kernel<32, 8><<<dim3(2, 8, 128), 256, 0, stream>>>(h2, w3, b3, h3, 56, 56, 64);
    // fc1
    fc1_stageA<<<dim3(4, 4, 16), 256, 0, stream>>>(h3, wf1, pa);
    fc1_stageB<<<64, 256, 0, stream>>>(pa, bf1, f1);
    // fc2
    fc2_kernel<<<500, 256, 0, stream>>>(f1, wf2, bf2, (float*)d_out);
}

// Round 4
// 321.570 us; speedup vs baseline: 15.6294x; 1.8591x over previous
//
#include <hip/hip_runtime.h>

typedef __attribute__((ext_vector_type(8))) short short8;
typedef __attribute__((ext_vector_type(4))) float f32x4;
typedef unsigned short ushort;
typedef unsigned int uint;

static __device__ __forceinline__ float sgn(float v) {
    return (v > 0.f) ? 1.f : ((v < 0.f) ? -1.f : 0.f);
}
static __device__ __forceinline__ ushort f2bf(float f) {
    uint u = __builtin_bit_cast(uint, f);
    u += 0x7fffu + ((u >> 16) & 1u);   // RNE
    return (ushort)(u >> 16);
}
static __device__ __forceinline__ ushort sgn2bf(float v) {
    return (v > 0.f) ? (ushort)0x3F80 : ((v < 0.f) ? (ushort)0xBF80 : (ushort)0);
}

// ---------------- pad-zero: zero the halo borders of h1p and h2p ----------------
__global__ void pad_zero(ushort* __restrict__ h1p, ushort* __restrict__ h2p) {
    int t = blockIdx.x * 256 + threadIdx.x;
    if (t < 925696) {                       // h1p: 128 b x 452 cells x 16 ch
        int b = t / 7232, r = t % 7232;
        int cell = r >> 4, ch = r & 15;
        int y, x;
        if (cell < 114)      { y = 0;   x = cell; }
        else if (cell < 228) { y = 113; x = cell - 114; }
        else { int s = cell - 228; y = 1 + (s >> 1); x = (s & 1) ? 113 : 0; }
        h1p[((b * 114 + y) * 114 + x) * 16 + ch] = 0;
    } else {
        t -= 925696;
        if (t >= 933888) return;            // h2p: 128 b x 228 cells x 32 ch
        int b = t / 7296, r = t % 7296;
        int cell = r >> 5, ch = r & 31;
        int y, x;
        if (cell < 58)       { y = 0;  x = cell; }
        else if (cell < 116) { y = 57; x = cell - 58; }
        else { int s = cell - 116; y = 1 + (s >> 1); x = (s & 1) ? 57 : 0; }
        h2p[((b * 58 + y) * 58 + x) * 32 + ch] = 0;
    }
}

// ---------------- weight-fragment prep (sgn -> bf16, MFMA fragment order) -------
// conv2: K-layout k = ky*48 + kx*16 + ci  (K=144, padded to 160 = 5 calls)
//   f2[((c*2 + n)*64 + l)*8 + j]: co = n*16 + (l&15), k = c*32 + (l>>4)*8 + j
// conv3: K-layout k = ky*96 + kx*32 + ci  (K=288 = 9 calls)
//   f3[((c*4 + n)*64 + l)*8 + j]
__global__ void wfrag_prep(const float* __restrict__ w2, const float* __restrict__ w3,
                           ushort* __restrict__ f2, ushort* __restrict__ f3) {
    int t = blockIdx.x * 256 + threadIdx.x;
    if (t < 5120) {
        int j = t & 7, l = (t >> 3) & 63, nc = t >> 9;  // nc = c*2 + n
        int n = nc & 1, c = nc >> 1;
        int k = c * 32 + ((l >> 4) << 3) + j;
        ushort v = 0;
        if (k < 144) {
            int ky = k / 48, rem = k % 48, kx = rem >> 4, ci = rem & 15;
            int co = n * 16 + (l & 15);
            v = sgn2bf(w2[((co * 16 + ci) * 3 + ky) * 3 + kx]);
        }
        f2[t] = v;
    } else {
        int t2 = t - 5120;
        if (t2 >= 18432) return;
        int j = t2 & 7, l = (t2 >> 3) & 63, nc = t2 >> 9;  // nc = c*4 + n
        int n = nc & 3, c = nc >> 2;
        int k = c * 32 + ((l >> 4) << 3) + j;               // < 288
        int ky = k / 96, rem = k % 96, kx = rem >> 5, ci = rem & 31;
        int co = n * 16 + (l & 15);
        f3[t2] = sgn2bf(w3[((co * 32 + ci) * 3 + ky) * 3 + kx]);
    }
}

// ---------------- conv1: fp32 direct (CIN=3), writes padded-NHWC bf16 -----------
// grid (25, 2, 128), block 256. Each thread: 8 co x 2 pooled px.
__global__ void conv1_kernel(const float* __restrict__ x,   // [128,3,224,224]
                             const float* __restrict__ w,   // [16,3,3,3]
                             const float* __restrict__ bias,
                             ushort* __restrict__ h1p) {    // [128,114,114,16]
    const int H = 224, W = 224;
    const int cog = blockIdx.y * 8;
    const int b   = blockIdx.z;

    __shared__ __align__(16) float wl[8][3][12];
    for (int i = threadIdx.x; i < 8 * 3 * 9; i += 256) {
        int co = i / 27, rem = i % 27;
        wl[co][rem / 9][rem % 9] = sgn(w[(size_t)(cog + co) * 27 + rem]);
    }
    __syncthreads();

    const int p2 = blockIdx.x * 256 + threadIdx.x;   // pooled-pixel pair id
    if (p2 >= 112 * 56) return;
    const int py = p2 / 56, px2 = p2 % 56;
    const int y0 = 2 * py - 1, x0 = 4 * px2 - 1;
    const bool interior = (y0 >= 0) && (y0 + 3 < H) && (x0 >= 0) && (x0 + 5 < W);

    float acc[8][8];
#pragma unroll
    for (int c = 0; c < 8; ++c)
#pragma unroll
        for (int q = 0; q < 8; ++q) acc[c][q] = 0.f;

    const float* xb = x + ((size_t)b * 3) * H * W;
    for (int ci = 0; ci < 3; ++ci) {
        const float* xc = xb + (size_t)ci * H * W;
        float in[4][6];
        if (interior) {
#pragma unroll
            for (int r = 0; r < 4; ++r) {
                const float* row = xc + (size_t)(y0 + r) * W + x0;
                in[r][0] = row[0];
                const float4 m = *(const float4*)(row + 1);
                in[r][1] = m.x; in[r][2] = m.y; in[r][3] = m.z; in[r][4] = m.w;
                in[r][5] = row[5];
            }
        } else {
#pragma unroll
            for (int r = 0; r < 4; ++r) {
                const int iy = y0 + r;
                const bool yok = ((unsigned)iy < (unsigned)H);
#pragma unroll
                for (int c = 0; c < 6; ++c) {
                    const int ix = x0 + c;
                    in[r][c] = (yok && ((unsigned)ix < (unsigned)W))
                                   ? xc[(size_t)iy * W + ix] : 0.f;
                }
            }
        }
#pragma unroll
        for (int co = 0; co < 8; ++co) {
            const float4* w4 = (const float4*)wl[co][ci];
            const float4 wA = w4[0], wB = w4[1], wC = w4[2];
            const float wv[9] = {wA.x, wA.y, wA.z, wA.w, wB.x, wB.y, wB.z, wB.w, wC.x};
#pragma unroll
            for (int ky = 0; ky < 3; ++ky)
#pragma unroll
                for (int kx = 0; kx < 3; ++kx) {
                    const float wgt = wv[ky * 3 + kx];
#pragma unroll
                    for (int u = 0; u < 2; ++u)
#pragma unroll
                        for (int sy = 0; sy < 2; ++sy)
#pragma unroll
                            for (int sx = 0; sx < 2; ++sx)
                                acc[co][u * 4 + sy * 2 + sx] =
                                    fmaf(wgt, in[sy + ky][2 * u + sx + kx],
                                         acc[co][u * 4 + sy * 2 + sx]);
                }
        }
    }

    // two output sites, 8 contiguous bf16 channels each (16 B stores)
#pragma unroll
    for (int u = 0; u < 2; ++u) {
        ushort pk[8];
#pragma unroll
        for (int co = 0; co < 8; ++co) {
            const float bv = bias[cog + co];
            float m = fmaxf(fmaxf(acc[co][u * 4 + 0], acc[co][u * 4 + 1]),
                            fmaxf(acc[co][u * 4 + 2], acc[co][u * 4 + 3]));
            pk[co] = f2bf(fmaxf(m + bv, 0.f));
        }
        ushort* dst = &h1p[(((size_t)b * 114 + 1 + py) * 114 + (1 + 2 * px2 + u)) * 16 + cog];
        *(short8*)dst = *(const short8*)pk;
    }
}

// ---------------- conv2: MFMA im2col GEMM, pooled, padded-NHWC bf16 -------------
// grid (56, 1, 128), block 256 = 4 waves: wave -> (row r = w>>1, co-tile n = w&1)
__global__ __launch_bounds__(256) void
conv2_mfma(const ushort* __restrict__ h1p,   // [128,114,114,16] bf16
           const ushort* __restrict__ wfrag, // [5][2][64][8] bf16
           const float* __restrict__ bias,   // [32]
           ushort* __restrict__ h2p) {       // [128,58,58,32] bf16
    const int py = blockIdx.x;               // pooled row 0..55
    const int b  = blockIdx.z;
    const int wv = threadIdx.x >> 6, l = threadIdx.x & 63;
    const int r = wv >> 1, n = wv & 1;
    const int y = 2 * py + r;                // pre-pool row 0..111
    const int lhi = l >> 4, llo = l & 15;

    __shared__ float lds[2][112][33];

    short8 wf[5];
#pragma unroll
    for (int c = 0; c < 5; ++c)
        wf[c] = *(const short8*)&wfrag[(((c * 2 + n) * 64) + l) * 8];

    int base_el[5];  bool vld[5];
#pragma unroll
    for (int c = 0; c < 5; ++c) {
        int cc = c * 4 + lhi;               // 8-elem chunk id, 0..19
        int dy = cc / 6, off = (cc % 6) * 8;
        vld[c] = (cc < 18);
        base_el[c] = (((b * 114 + y + dy) * 114) * 16) + off;
    }

    f32x4 acc[7];
#pragma unroll
    for (int m = 0; m < 7; ++m) acc[m] = (f32x4){0.f, 0.f, 0.f, 0.f};

#pragma unroll
    for (int m = 0; m < 7; ++m) {
        const int xe = (m * 16 + llo) * 16;
#pragma unroll
        for (int c = 0; c < 5; ++c) {
            short8 a = {};
            if (vld[c]) a = *(const short8*)&h1p[base_el[c] + xe];
            acc[m] = __builtin_amdgcn_mfma_f32_16x16x32_bf16(a, wf[c], acc[m], 0, 0, 0);
        }
    }

    // D: pixel = m*16 + (l>>4)*4 + j, co = n*16 + (l&15)
#pragma unroll
    for (int m = 0; m < 7; ++m)
#pragma unroll
        for (int j = 0; j < 4; ++j)
            lds[r][m * 16 + lhi * 4 + j][n * 16 + llo] = acc[m][j];
    __syncthreads();

    // pool 2x2 + bias + relu -> h2p interior
#pragma unroll
    for (int i = 0; i < 7; ++i) {
        int o = threadIdx.x + i * 256;       // 0..1791
        int px = o >> 5, co = o & 31;
        float v = fmaxf(fmaxf(lds[0][2 * px][co], lds[0][2 * px + 1][co]),
                        fmaxf(lds[1][2 * px][co], lds[1][2 * px + 1][co]));
        v = fmaxf(v + bias[co], 0.f);
        h2p[(((size_t)b * 58 + 1 + py) * 58 + 1 + px) * 32 + co] = f2bf(v);
    }
}

// ---------------- conv3: MFMA im2col GEMM, pooled, NCHW fp32 out ----------------
// grid (28, 1, 128), block 256 = 4 waves: wave w = co-tile n (0..3), all 112 px
__global__ __launch_bounds__(256) void
conv3_mfma(const ushort* __restrict__ h2p,   // [128,58,58,32] bf16
           const ushort* __restrict__ wfrag, // [9][4][64][8] bf16
           const float* __restrict__ bias,   // [64]
           float* __restrict__ h3) {         // [128,64,28,28] fp32
    const int py = blockIdx.x;               // pooled row 0..27
    const int b  = blockIdx.z;
    const int n = threadIdx.x >> 6, l = threadIdx.x & 63;
    const int lhi = l >> 4, llo = l & 15;

    __shared__ float lds[112][65];

    short8 wf[9];
#pragma unroll
    for (int c = 0; c < 9; ++c)
        wf[c] = *(const short8*)&wfrag[(((c * 4 + n) * 64) + l) * 8];

    int rowbase[9];
#pragma unroll
    for (int c = 0; c < 9; ++c) {
        int cc = c * 4 + lhi;               // 0..35
        int dy = cc / 12, off = (cc % 12) * 8;
        rowbase[c] = (((b * 58 + 2 * py + dy) * 58) * 32) + off;
    }

    f32x4 acc[7];
#pragma unroll
    for (int m = 0; m < 7; ++m) acc[m] = (f32x4){0.f, 0.f, 0.f, 0.f};

#pragma unroll
    for (int m = 0; m < 7; ++m) {
        const int p = m * 16 + llo;          // pixel 0..111 (row-major 2x56)
        const int prow = (p >= 56) ? 1 : 0;
        const int add = prow * (58 * 32) + (p - 56 * prow) * 32;
#pragma unroll
        for (int c = 0; c < 9; ++c) {
            short8 a = *(const short8*)&h2p[rowbase[c] + add];
            acc[m] = __builtin_amdgcn_mfma_f32_16x16x32_bf16(a, wf[c], acc[m], 0, 0, 0);
        }
    }

#pragma unroll
    for (int m = 0; m < 7; ++m)
#pragma unroll
        for (int j = 0; j < 4; ++j)
            lds[m * 16 + lhi * 4 + j][n * 16 + llo] = acc[m][j];
    __syncthreads();

#pragma unroll
    for (int i = 0; i < 7; ++i) {
        int o = threadIdx.x + i * 256;       // 0..1791
        int px = o % 28, co = o / 28;
        float v = fmaxf(fmaxf(lds[2 * px][co], lds[2 * px + 1][co]),
                        fmaxf(lds[56 + 2 * px][co], lds[57 + 2 * px][co]));
        v = fmaxf(v + bias[co], 0.f);
        h3[(((size_t)b * 64 + co) * 28 + py) * 28 + px] = v;
    }
}

// ---------------- FC1 stage A/B and FC2: unchanged (known good) -----------------
__global__ void fc1_stageA(const float* __restrict__ act,
                           const float* __restrict__ wf,
                           float* __restrict__ partials) {
    const int K = 50176, KSPLIT = 3136, KC = 64;
    const int bt = blockIdx.x * 32, ct = blockIdx.y * 32, ks = blockIdx.z;
    const int tx = threadIdx.x & 15, ty = threadIdx.x >> 4;

    __shared__ __align__(16) float A[32][68];
    __shared__ __align__(16) float Wl[32][68];

    float a00 = 0.f, a01 = 0.f, a10 = 0.f, a11 = 0.f;
    const int k_base = ks * KSPLIT;
    for (int k0 = k_base; k0 < k_base + KSPLIT; k0 += KC) {
        __syncthreads();
#pragma unroll
        for (int j = 0; j < 2; ++j) {
            const int s = threadIdx.x + j * 256;
            const int r = s >> 4, c4 = (s & 15) * 4;
            const float4 av = *(const float4*)&act[(size_t)(bt + r) * K + k0 + c4];
            *(float4*)&A[r][c4] = av;
            float4 wvv = *(const float4*)&wf[(size_t)(ct + r) * K + k0 + c4];
            wvv.x = sgn(wvv.x); wvv.y = sgn(wvv.y); wvv.z = sgn(wvv.z); wvv.w = sgn(wvv.w);
            *(float4*)&Wl[r][c4] = wvv;
        }
        __syncthreads();
#pragma unroll
        for (int k4 = 0; k4 < 16; ++k4) {
            const float4 x0 = *(const float4*)&A[ty][k4 * 4];
            const float4 x1 = *(const float4*)&A[ty + 16][k4 * 4];
            const float4 w0 = *(const float4*)&Wl[tx][k4 * 4];
            const float4 w1 = *(const float4*)&Wl[tx + 16][k4 * 4];
            a00 = fmaf(x0.x, w0.x, fmaf(x0.y, w0.y, fmaf(x0.z, w0.z, fmaf(x0.w, w0.w, a00))));
            a01 = fmaf(x0.x, w1.x, fmaf(x0.y, w1.y, fmaf(x0.z, w1.z, fmaf(x0.w, w1.w, a01))));
            a10 = fmaf(x1.x, w0.x, fmaf(x1.y, w0.y, fmaf(x1.z, w0.z, fmaf(x1.w, w0.w, a10))));
            a11 = fmaf(x1.x, w1.x, fmaf(x1.y, w1.y, fmaf(x1.z, w1.z, fmaf(x1.w, w1.w, a11))));
        }
    }
    float* pb = partials + (size_t)ks * 128 * 128;
    pb[(bt + ty)      * 128 + ct + tx]      = a00;
    pb[(bt + ty)      * 128 + ct + tx + 16] = a01;
    pb[(bt + ty + 16) * 128 + ct + tx]      = a10;
    pb[(bt + ty + 16) * 128 + ct + tx + 16] = a11;
}

__global__ void fc1_stageB(const float* __restrict__ partials,
                           const float* __restrict__ bf,
                           float* __restrict__ f1) {
    const int o = blockIdx.x * 256 + threadIdx.x;
    float acc = 0.f;
#pragma unroll
    for (int ks = 0; ks < 16; ++ks) acc += partials[(size_t)ks * 16384 + o];
    f1[o] = fmaxf(acc + bf[o & 127], 0.f);
}

__global__ void fc2_kernel(const float* __restrict__ act,
                           const float* __restrict__ wf,
                           const float* __restrict__ bf,
                           float* __restrict__ out) {
    const int o = blockIdx.x * 256 + threadIdx.x;
    if (o >= 128 * 1000) return;
    const int b = o / 1000, co = o % 1000;
    const float* a  = act + b * 128;
    const float* wr = wf + co * 128;
    float acc = 0.f;
#pragma unroll 8
    for (int k = 0; k < 128; ++k)
        acc = fmaf(a[k], sgn(wr[k]), acc);
    out[o] = acc + bf[co];
}

extern "C" void kernel_launch(void* const* d_in, const int* in_sizes, int n_in,
                              void* d_out, int out_size, void* d_ws, size_t ws_size,
                              hipStream_t stream) {
    const float* x   = (const float*)d_in[0];
    const float* w1  = (const float*)d_in[1];
    const float* b1  = (const float*)d_in[2];
    const float* w2  = (const float*)d_in[3];
    const float* b2  = (const float*)d_in[4];
    const float* w3  = (const float*)d_in[5];
    const float* b3  = (const float*)d_in[6];
    const float* wf1 = (const float*)d_in[7];
    const float* bf1 = (const float*)d_in[8];
    const float* wf2 = (const float*)d_in[9];
    const float* bf2 = (const float*)d_in[10];

    // ws layout:
    //   h1p  bf16 [128,114,114,16] @ 0            (53,231,616 B)
    //   h2p  bf16 [128,58,58,32]   @ 53,231,616   (27,557,888 B)
    //   h3   fp32 [128,64,28,28]   @ 80,789,504   (25,690,112 B)
    //   partials fp32 [16][16384]  @ 106,479,616  ( 1,048,576 B)
    //   f1   fp32 [128,128]        @ 107,528,192  (    65,536 B)
    //   wfrag2 bf16 5*2*64*8       @ 107,593,728  (    10,240 B)
    //   wfrag3 bf16 9*4*64*8       @ 107,603,968  (    36,864 B)
    char* ws = (char*)d_ws;
    ushort* h1p = (ushort*)ws;
    ushort* h2p = (ushort*)(ws + 53231616u);
    float*  h3  = (float*) (ws + 80789504u);
    float*  pa  = (float*) (ws + 106479616u);
    float*  f1  = (float*) (ws + 107528192u);
    ushort* wf2frag = (ushort*)(ws + 107593728u);
    ushort* wf3frag = (ushort*)(ws + 107603968u);

    pad_zero<<<7265, 256, 0, stream>>>(h1p, h2p);
    wfrag_prep<<<92, 256, 0, stream>>>(w2, w3, wf2frag, wf3frag);
    conv1_kernel<<<dim3(25, 2, 128), 256, 0, stream>>>(x, w1, b1, h1p);
    conv2_mfma<<<dim3(56, 1, 128), 256, 0, stream>>>(h1p, wf2frag, b2, h2p);
    conv3_mfma<<<dim3(28, 1, 128), 256, 0, stream>>>(h2p, wf3frag, b3, h3);
    fc1_stageA<<<dim3(4, 4, 16), 256, 0, stream>>>(h3, wf1, pa);
    fc1_stageB<<<64, 256, 0, stream>>>(pa, bf1, f1);
    fc2_kernel<<<500, 256, 0, stream>>>(f1, wf2, bf2, (float*)d_out);
}

// Round 5
// 317.541 us; speedup vs baseline: 15.8277x; 1.0127x over previous
//
#include <hip/hip_runtime.h>

typedef __attribute__((ext_vector_type(8))) short short8;
typedef __attribute__((ext_vector_type(4))) float f32x4;
typedef __attribute__((ext_vector_type(4), aligned(4))) float f32x4u;  // 4B-aligned vec load
typedef unsigned short ushort;
typedef unsigned int uint;

static __device__ __forceinline__ float sgn(float v) {
    return (v > 0.f) ? 1.f : ((v < 0.f) ? -1.f : 0.f);
}
static __device__ __forceinline__ ushort f2bf(float f) {
    uint u = __builtin_bit_cast(uint, f);
    u += 0x7fffu + ((u >> 16) & 1u);   // RNE
    return (ushort)(u >> 16);
}
static __device__ __forceinline__ ushort sgn2bf(float v) {
    return (v > 0.f) ? (ushort)0x3F80 : ((v < 0.f) ? (ushort)0xBF80 : (ushort)0);
}

// ---------------- pad-zero: zero the halo borders of h1p and h2p ----------------
__global__ void pad_zero(ushort* __restrict__ h1p, ushort* __restrict__ h2p) {
    int t = blockIdx.x * 256 + threadIdx.x;
    if (t < 925696) {                       // h1p: 128 b x 452 cells x 16 ch
        int b = t / 7232, r = t % 7232;
        int cell = r >> 4, ch = r & 15;
        int y, x;
        if (cell < 114)      { y = 0;   x = cell; }
        else if (cell < 228) { y = 113; x = cell - 114; }
        else { int s = cell - 228; y = 1 + (s >> 1); x = (s & 1) ? 113 : 0; }
        h1p[((b * 114 + y) * 114 + x) * 16 + ch] = 0;
    } else {
        t -= 925696;
        if (t >= 933888) return;            // h2p: 128 b x 228 cells x 32 ch
        int b = t / 7296, r = t % 7296;
        int cell = r >> 5, ch = r & 31;
        int y, x;
        if (cell < 58)       { y = 0;  x = cell; }
        else if (cell < 116) { y = 57; x = cell - 58; }
        else { int s = cell - 116; y = 1 + (s >> 1); x = (s & 1) ? 57 : 0; }
        h2p[((b * 58 + y) * 58 + x) * 32 + ch] = 0;
    }
}

// ---------------- weight-fragment prep (sgn -> bf16, MFMA fragment order) -------
__global__ void wfrag_prep(const float* __restrict__ w2, const float* __restrict__ w3,
                           ushort* __restrict__ f2, ushort* __restrict__ f3) {
    int t = blockIdx.x * 256 + threadIdx.x;
    if (t < 5120) {
        int j = t & 7, l = (t >> 3) & 63, nc = t >> 9;  // nc = c*2 + n
        int n = nc & 1, c = nc >> 1;
        int k = c * 32 + ((l >> 4) << 3) + j;
        ushort v = 0;
        if (k < 144) {
            int ky = k / 48, rem = k % 48, kx = rem >> 4, ci = rem & 15;
            int co = n * 16 + (l & 15);
            v = sgn2bf(w2[((co * 16 + ci) * 3 + ky) * 3 + kx]);
        }
        f2[t] = v;
    } else {
        int t2 = t - 5120;
        if (t2 >= 18432) return;
        int j = t2 & 7, l = (t2 >> 3) & 63, nc = t2 >> 9;  // nc = c*4 + n
        int n = nc & 3, c = nc >> 2;
        int k = c * 32 + ((l >> 4) << 3) + j;               // < 288
        int ky = k / 96, rem = k % 96, kx = rem >> 5, ci = rem & 31;
        int co = n * 16 + (l & 15);
        f3[t2] = sgn2bf(w3[((co * 32 + ci) * 3 + ky) * 3 + kx]);
    }
}

// ---------------- conv1: fp32 direct, 1 thread = 1 pooled px x ALL 16 co --------
// Writes full 32B NHWC pixels, adjacent lanes -> adjacent pixels (coalesced).
// grid (49, 1, 128), block 256.
__global__ void conv1_kernel(const float* __restrict__ x,   // [128,3,224,224]
                             const float* __restrict__ w,   // [16,3,3,3]
                             const float* __restrict__ bias,
                             ushort* __restrict__ h1p) {    // [128,114,114,16]
    const int H = 224, W = 224;
    const int b = blockIdx.z;

    __shared__ __align__(16) float wl[16][3][12];
    __shared__ float bl[16];
    for (int i = threadIdx.x; i < 16 * 27; i += 256) {
        int co = i / 27, rem = i % 27;
        wl[co][rem / 9][rem % 9] = sgn(w[co * 27 + rem]);
    }
    if (threadIdx.x < 16) bl[threadIdx.x] = bias[threadIdx.x];
    __syncthreads();

    const int p = blockIdx.x * 256 + threadIdx.x;   // 0..12543
    const int py = p / 112, px = p % 112;
    const int y0 = 2 * py - 1, x0 = 2 * px - 1;
    const bool interior = (y0 >= 0) && (y0 + 3 < H) && (x0 >= 0) && (x0 + 3 < W);

    float acc[16][4];
#pragma unroll
    for (int c = 0; c < 16; ++c)
#pragma unroll
        for (int q = 0; q < 4; ++q) acc[c][q] = 0.f;

    const float* xb = x + ((size_t)b * 3) * H * W;
    for (int ci = 0; ci < 3; ++ci) {
        const float* xc = xb + (size_t)ci * H * W;
        float in[4][4];
        if (interior) {
#pragma unroll
            for (int r = 0; r < 4; ++r) {
                const f32x4u v = *(const f32x4u*)(xc + (size_t)(y0 + r) * W + x0);
                in[r][0] = v.x; in[r][1] = v.y; in[r][2] = v.z; in[r][3] = v.w;
            }
        } else {
#pragma unroll
            for (int r = 0; r < 4; ++r) {
                const int iy = y0 + r;
                const bool yok = ((unsigned)iy < (unsigned)H);
#pragma unroll
                for (int c = 0; c < 4; ++c) {
                    const int ix = x0 + c;
                    in[r][c] = (yok && ((unsigned)ix < (unsigned)W))
                                   ? xc[(size_t)iy * W + ix] : 0.f;
                }
            }
        }
#pragma unroll
        for (int co = 0; co < 16; ++co) {
            const f32x4* w4 = (const f32x4*)wl[co][ci];
            const f32x4 wA = w4[0], wB = w4[1], wC = w4[2];
            const float wv[9] = {wA.x, wA.y, wA.z, wA.w, wB.x, wB.y, wB.z, wB.w, wC.x};
#pragma unroll
            for (int ky = 0; ky < 3; ++ky)
#pragma unroll
                for (int kx = 0; kx < 3; ++kx) {
                    const float wgt = wv[ky * 3 + kx];
                    acc[co][0] = fmaf(wgt, in[ky][kx],         acc[co][0]);
                    acc[co][1] = fmaf(wgt, in[ky][kx + 1],     acc[co][1]);
                    acc[co][2] = fmaf(wgt, in[ky + 1][kx],     acc[co][2]);
                    acc[co][3] = fmaf(wgt, in[ky + 1][kx + 1], acc[co][3]);
                }
        }
    }

    ushort pk[16];
#pragma unroll
    for (int co = 0; co < 16; ++co) {
        float m = fmaxf(fmaxf(acc[co][0], acc[co][1]), fmaxf(acc[co][2], acc[co][3]));
        pk[co] = f2bf(fmaxf(m + bl[co], 0.f));
    }
    ushort* dst = &h1p[(((size_t)b * 114 + 1 + py) * 114 + (1 + px)) * 16];
    *(short8*)dst       = *(const short8*)&pk[0];
    *(short8*)(dst + 8) = *(const short8*)&pk[8];
}

// ---------------- conv2: MFMA im2col GEMM, pooled, padded-NHWC bf16 -------------
// grid (56, 1, 128), block 256 = 4 waves: wave -> (row r = w>>1, co-tile n = w&1)
__global__ __launch_bounds__(256) void
conv2_mfma(const ushort* __restrict__ h1p,   // [128,114,114,16] bf16
           const ushort* __restrict__ wfrag, // [5][2][64][8] bf16
           const float* __restrict__ bias,   // [32]
           ushort* __restrict__ h2p) {       // [128,58,58,32] bf16
    const int py = blockIdx.x;               // pooled row 0..55
    const int b  = blockIdx.z;
    const int wv = threadIdx.x >> 6, l = threadIdx.x & 63;
    const int r = wv >> 1, n = wv & 1;
    const int y = 2 * py + r;                // pre-pool row 0..111
    const int lhi = l >> 4, llo = l & 15;

    __shared__ float lds[2][112][33];

    short8 wf[5];
#pragma unroll
    for (int c = 0; c < 5; ++c)
        wf[c] = *(const short8*)&wfrag[(((c * 2 + n) * 64) + l) * 8];

    int base_el[5];  bool vld[5];
#pragma unroll
    for (int c = 0; c < 5; ++c) {
        int cc = c * 4 + lhi;               // 8-elem chunk id, 0..19
        int dy = cc / 6, off = (cc % 6) * 8;
        vld[c] = (cc < 18);
        base_el[c] = (((b * 114 + y + dy) * 114) * 16) + off;
    }

    f32x4 acc[7];
#pragma unroll
    for (int m = 0; m < 7; ++m) acc[m] = (f32x4){0.f, 0.f, 0.f, 0.f};

#pragma unroll
    for (int m = 0; m < 7; ++m) {
        const int xe = (m * 16 + llo) * 16;
#pragma unroll
        for (int c = 0; c < 5; ++c) {
            short8 a = {};
            if (vld[c]) a = *(const short8*)&h1p[base_el[c] + xe];
            acc[m] = __builtin_amdgcn_mfma_f32_16x16x32_bf16(a, wf[c], acc[m], 0, 0, 0);
        }
    }

    // D: pixel = m*16 + (l>>4)*4 + j, co = n*16 + (l&15)
#pragma unroll
    for (int m = 0; m < 7; ++m)
#pragma unroll
        for (int j = 0; j < 4; ++j)
            lds[r][m * 16 + lhi * 4 + j][n * 16 + llo] = acc[m][j];
    __syncthreads();

    // pool 2x2 + bias + relu -> h2p interior
#pragma unroll
    for (int i = 0; i < 7; ++i) {
        int o = threadIdx.x + i * 256;       // 0..1791
        int px = o >> 5, co = o & 31;
        float v = fmaxf(fmaxf(lds[0][2 * px][co], lds[0][2 * px + 1][co]),
                        fmaxf(lds[1][2 * px][co], lds[1][2 * px + 1][co]));
        v = fmaxf(v + bias[co], 0.f);
        h2p[(((size_t)b * 58 + 1 + py) * 58 + 1 + px) * 32 + co] = f2bf(v);
    }
}

// ---------------- conv3: MFMA im2col GEMM, pooled, NCHW fp32 out ----------------
// grid (28, 1, 128), block 256 = 4 waves: wave w = co-tile n (0..3), all 112 px
__global__ __launch_bounds__(256) void
conv3_mfma(const ushort* __restrict__ h2p,   // [128,58,58,32] bf16
           const ushort* __restrict__ wfrag, // [9][4][64][8] bf16
           const float* __restrict__ bias,   // [64]
           float* __restrict__ h3) {         // [128,64,28,28] fp32
    const int py = blockIdx.x;               // pooled row 0..27
    const int b  = blockIdx.z;
    const int n = threadIdx.x >> 6, l = threadIdx.x & 63;
    const int lhi = l >> 4, llo = l & 15;

    __shared__ float lds[112][65];

    short8 wf[9];
#pragma unroll
    for (int c = 0; c < 9; ++c)
        wf[c] = *(const short8*)&wfrag[(((c * 4 + n) * 64) + l) * 8];

    int rowbase[9];
#pragma unroll
    for (int c = 0; c < 9; ++c) {
        int cc = c * 4 + lhi;               // 0..35
        int dy = cc / 12, off = (cc % 12) * 8;
        rowbase[c] = (((b * 58 + 2 * py + dy) * 58) * 32) + off;
    }

    f32x4 acc[7];
#pragma unroll
    for (int m = 0; m < 7; ++m) acc[m] = (f32x4){0.f, 0.f, 0.f, 0.f};

#pragma unroll
    for (int m = 0; m < 7; ++m) {
        const int p = m * 16 + llo;          // pixel 0..111 (row-major 2x56)
        const int prow = (p >= 56) ? 1 : 0;
        const int add = prow * (58 * 32) + (p - 56 * prow) * 32;
#pragma unroll
        for (int c = 0; c < 9; ++c) {
            short8 a = *(const short8*)&h2p[rowbase[c] + add];
            acc[m] = __builtin_amdgcn_mfma_f32_16x16x32_bf16(a, wf[c], acc[m], 0, 0, 0);
        }
    }

#pragma unroll
    for (int m = 0; m < 7; ++m)
#pragma unroll
        for (int j = 0; j < 4; ++j)
            lds[m * 16 + lhi * 4 + j][n * 16 + llo] = acc[m][j];
    __syncthreads();

#pragma unroll
    for (int i = 0; i < 7; ++i) {
        int o = threadIdx.x + i * 256;       // 0..1791
        int px = o % 28, co = o / 28;
        float v = fmaxf(fmaxf(lds[2 * px][co], lds[2 * px + 1][co]),
                        fmaxf(lds[56 + 2 * px][co], lds[57 + 2 * px][co]));
        v = fmaxf(v + bias[co], 0.f);
        h3[(((size_t)b * 64 + co) * 28 + py) * 28 + px] = v;
    }
}

// ---------------- FC1 stage A/B and FC2: unchanged (known good) -----------------
__global__ void fc1_stageA(const float* __restrict__ act,
                           const float* __restrict__ wf,
                           float* __restrict__ partials) {
    const int K = 50176, KSPLIT = 3136, KC = 64;
    const int bt = blockIdx.x * 32, ct = blockIdx.y * 32, ks = blockIdx.z;
    const int tx = threadIdx.x & 15, ty = threadIdx.x >> 4;

    __shared__ __align__(16) float A[32][68];
    __shared__ __align__(16) float Wl[32][68];

    float a00 = 0.f, a01 = 0.f, a10 = 0.f, a11 = 0.f;
    const int k_base = ks * KSPLIT;
    for (int k0 = k_base; k0 < k_base + KSPLIT; k0 += KC) {
        __syncthreads();
#pragma unroll
        for (int j = 0; j < 2; ++j) {
            const int s = threadIdx.x + j * 256;
            const int r = s >> 4, c4 = (s & 15) * 4;
            const float4 av = *(const float4*)&act[(size_t)(bt + r) * K + k0 + c4];
            *(float4*)&A[r][c4] = av;
            float4 wvv = *(const float4*)&wf[(size_t)(ct + r) * K + k0 + c4];
            wvv.x = sgn(wvv.x); wvv.y = sgn(wvv.y); wvv.z = sgn(wvv.z); wvv.w = sgn(wvv.w);
            *(float4*)&Wl[r][c4] = wvv;
        }
        __syncthreads();
#pragma unroll
        for (int k4 = 0; k4 < 16; ++k4) {
            const float4 x0 = *(const float4*)&A[ty][k4 * 4];
            const float4 x1 = *(const float4*)&A[ty + 16][k4 * 4];
            const float4 w0 = *(const float4*)&Wl[tx][k4 * 4];
            const float4 w1 = *(const float4*)&Wl[tx + 16][k4 * 4];
            a00 = fmaf(x0.x, w0.x, fmaf(x0.y, w0.y, fmaf(x0.z, w0.z, fmaf(x0.w, w0.w, a00))));
            a01 = fmaf(x0.x, w1.x, fmaf(x0.y, w1.y, fmaf(x0.z, w1.z, fmaf(x0.w, w1.w, a01))));
            a10 = fmaf(x1.x, w0.x, fmaf(x1.y, w0.y, fmaf(x1.z, w0.z, fmaf(x1.w, w0.w, a10))));
            a11 = fmaf(x1.x, w1.x, fmaf(x1.y, w1.y, fmaf(x1.z, w1.z, fmaf(x1.w, w1.w, a11))));
        }
    }
    float* pb = partials + (size_t)ks * 128 * 128;
    pb[(bt + ty)      * 128 + ct + tx]      = a00;
    pb[(bt + ty)      * 128 + ct + tx + 16] = a01;
    pb[(bt + ty + 16) * 128 + ct + tx]      = a10;
    pb[(bt + ty + 16) * 128 + ct + tx + 16] = a11;
}

__global__ void fc1_stageB(const float* __restrict__ partials,
                           const float* __restrict__ bf,
                           float* __restrict__ f1) {
    const int o = blockIdx.x * 256 + threadIdx.x;
    float acc = 0.f;
#pragma unroll
    for (int ks = 0; ks < 16; ++ks) acc += partials[(size_t)ks * 16384 + o];
    f1[o] = fmaxf(acc + bf[o & 127], 0.f);
}

__global__ void fc2_kernel(const float* __restrict__ act,
                           const float* __restrict__ wf,
                           const float* __restrict__ bf,
                           float* __restrict__ out) {
    const int o = blockIdx.x * 256 + threadIdx.x;
    if (o >= 128 * 1000) return;
    const int b = o / 1000, co = o % 1000;
    const float* a  = act + b * 128;
    const float* wr = wf + co * 128;
    float acc = 0.f;
#pragma unroll 8
    for (int k = 0; k < 128; ++k)
        acc = fmaf(a[k], sgn(wr[k]), acc);
    out[o] = acc + bf[co];
}

extern "C" void kernel_launch(void* const* d_in, const int* in_sizes, int n_in,
                              void* d_out, int out_size, void* d_ws, size_t ws_size,
                              hipStream_t stream) {
    const float* x   = (const float*)d_in[0];
    const float* w1  = (const float*)d_in[1];
    const float* b1  = (const float*)d_in[2];
    const float* w2  = (const float*)d_in[3];
    const float* b2  = (const float*)d_in[4];
    const float* w3  = (const float*)d_in[5];
    const float* b3  = (const float*)d_in[6];
    const float* wf1 = (const float*)d_in[7];
    const float* bf1 = (const float*)d_in[8];
    const float* wf2 = (const float*)d_in[9];
    const float* bf2 = (const float*)d_in[10];

    // ws layout:
    //   h1p  bf16 [128,114,114,16] @ 0            (53,231,616 B)
    //   h2p  bf16 [128,58,58,32]   @ 53,231,616   (27,557,888 B)
    //   h3   fp32 [128,64,28,28]   @ 80,789,504   (25,690,112 B)
    //   partials fp32 [16][16384]  @ 106,479,616  ( 1,048,576 B)
    //   f1   fp32 [128,128]        @ 107,528,192  (    65,536 B)
    //   wfrag2 bf16 5*2*64*8       @ 107,593,728  (    10,240 B)
    //   wfrag3 bf16 9*4*64*8       @ 107,603,968  (    36,864 B)
    char* ws = (char*)d_ws;
    ushort* h1p = (ushort*)ws;
    ushort* h2p = (ushort*)(ws + 53231616u);
    float*  h3  = (float*) (ws + 80789504u);
    float*  pa  = (float*) (ws + 106479616u);
    float*  f1  = (float*) (ws + 107528192u);
    ushort* wf2frag = (ushort*)(ws + 107593728u);
    ushort* wf3frag = (ushort*)(ws + 107603968u);

    pad_zero<<<7265, 256, 0, stream>>>(h1p, h2p);
    wfrag_prep<<<92, 256, 0, stream>>>(w2, w3, wf2frag, wf3frag);
    conv1_kernel<<<dim3(49, 1, 128), 256, 0, stream>>>(x, w1, b1, h1p);
    conv2_mfma<<<dim3(56, 1, 128), 256, 0, stream>>>(h1p, wf2frag, b2, h2p);
    conv3_mfma<<<dim3(28, 1, 128), 256, 0, stream>>>(h2p, wf3frag, b3, h3);
    fc1_stageA<<<dim3(4, 4, 16), 256, 0, stream>>>(h3, wf1, pa);
    fc1_stageB<<<64, 256, 0, stream>>>(pa, bf1, f1);
    fc2_kernel<<<500, 256, 0, stream>>>(f1, wf2, bf2, (float*)d_out);
}

// Round 6
// 299.894 us; speedup vs baseline: 16.7591x; 1.0588x over previous
//
#include <hip/hip_runtime.h>

typedef __attribute__((ext_vector_type(8))) short short8;
typedef __attribute__((ext_vector_type(8), aligned(8))) short short8u;  // 8B-aligned 16B load
typedef __attribute__((ext_vector_type(4))) short short4v;
typedef __attribute__((ext_vector_type(4))) float f32x4;
typedef unsigned short ushort;
typedef unsigned int uint;

static __device__ __forceinline__ float sgn(float v) {
    return (v > 0.f) ? 1.f : ((v < 0.f) ? -1.f : 0.f);
}
static __device__ __forceinline__ ushort f2bf(float f) {
    uint u = __builtin_bit_cast(uint, f);
    u += 0x7fffu + ((u >> 16) & 1u);   // RNE
    return (ushort)(u >> 16);
}
static __device__ __forceinline__ ushort sgn2bf(float v) {
    return (v > 0.f) ? (ushort)0x3F80 : ((v < 0.f) ? (ushort)0xBF80 : (ushort)0);
}

// ---------------- pad-zero: zero the halo borders of h1p and h2p ----------------
__global__ void pad_zero(ushort* __restrict__ h1p, ushort* __restrict__ h2p) {
    int t = blockIdx.x * 256 + threadIdx.x;
    if (t < 925696) {                       // h1p: 128 b x 452 cells x 16 ch
        int b = t / 7232, r = t % 7232;
        int cell = r >> 4, ch = r & 15;
        int y, x;
        if (cell < 114)      { y = 0;   x = cell; }
        else if (cell < 228) { y = 113; x = cell - 114; }
        else { int s = cell - 228; y = 1 + (s >> 1); x = (s & 1) ? 113 : 0; }
        h1p[((b * 114 + y) * 114 + x) * 16 + ch] = 0;
    } else {
        t -= 925696;
        if (t >= 933888) return;            // h2p: 128 b x 228 cells x 32 ch
        int b = t / 7296, r = t % 7296;
        int cell = r >> 5, ch = r & 31;
        int y, x;
        if (cell < 58)       { y = 0;  x = cell; }
        else if (cell < 116) { y = 57; x = cell - 58; }
        else { int s = cell - 116; y = 1 + (s >> 1); x = (s & 1) ? 57 : 0; }
        h2p[((b * 58 + y) * 58 + x) * 32 + ch] = 0;
    }
}

// ---------------- x4_prep: x NCHW fp32 -> padded NHWC-4ch bf16 ------------------
// x4[128][226][226][4], ch3 = 0, 1-pixel zero halo. One thread = one padded pixel.
__global__ void x4_prep(const float* __restrict__ x,   // [128,3,224,224]
                        ushort* __restrict__ x4) {
    int t = blockIdx.x * 256 + threadIdx.x;
    if (t >= 128 * 51076) return;
    int b = t / 51076, pix = t % 51076;
    int Y = pix / 226, X = pix % 226;
    ushort pk[4] = {0, 0, 0, 0};
    if (Y >= 1 && Y <= 224 && X >= 1 && X <= 224) {
        const float* xb = x + ((size_t)b * 3) * 50176 + (Y - 1) * 224 + (X - 1);
        pk[0] = f2bf(xb[0]);
        pk[1] = f2bf(xb[50176]);
        pk[2] = f2bf(xb[100352]);
    }
    *(short4v*)&x4[(size_t)t * 4] = *(const short4v*)pk;
}

// ---------------- weight-fragment prep (sgn -> bf16, MFMA fragment order) -------
// conv2: k = ky*48 + kx*16 + ci (K=144 pad 160); conv3: k = ky*96 + kx*32 + ci (K=288)
// conv1: k = ky*16 + kx*4 + ci (K=27 pad 64); pads zero.
__global__ void wfrag_prep(const float* __restrict__ w2, const float* __restrict__ w3,
                           const float* __restrict__ w1,
                           ushort* __restrict__ f2, ushort* __restrict__ f3,
                           ushort* __restrict__ f1) {
    int t = blockIdx.x * 256 + threadIdx.x;
    if (t < 5120) {
        int j = t & 7, l = (t >> 3) & 63, nc = t >> 9;  // nc = c*2 + n
        int n = nc & 1, c = nc >> 1;
        int k = c * 32 + ((l >> 4) << 3) + j;
        ushort v = 0;
        if (k < 144) {
            int ky = k / 48, rem = k % 48, kx = rem >> 4, ci = rem & 15;
            int co = n * 16 + (l & 15);
            v = sgn2bf(w2[((co * 16 + ci) * 3 + ky) * 3 + kx]);
        }
        f2[t] = v;
    } else if (t < 23552) {
        int t2 = t - 5120;
        int j = t2 & 7, l = (t2 >> 3) & 63, nc = t2 >> 9;  // nc = c*4 + n
        int n = nc & 3, c = nc >> 2;
        int k = c * 32 + ((l >> 4) << 3) + j;               // < 288
        int ky = k / 96, rem = k % 96, kx = rem >> 5, ci = rem & 31;
        int co = n * 16 + (l & 15);
        f3[t2] = sgn2bf(w3[((co * 32 + ci) * 3 + ky) * 3 + kx]);
    } else {
        int t1 = t - 23552;
        if (t1 >= 1024) return;
        int j = t1 & 7, l = (t1 >> 3) & 63, c = t1 >> 9;    // c = 0,1
        int k = c * 32 + ((l >> 4) << 3) + j;               // 0..63
        int ky = k >> 4, kx = (k >> 2) & 3, ci = k & 3;
        ushort v = 0;
        if (ky < 3 && kx < 3 && ci < 3) {
            int co = l & 15;
            v = sgn2bf(w1[((co * 3 + ci) * 3 + ky) * 3 + kx]);
        }
        f1[t1] = v;
    }
}

// ---------------- conv1: MFMA im2col GEMM (K=27 pad 64), pooled, NHWC bf16 ------
// grid (112, 1, 128), block 256 = 4 waves; wave wv covers m-tiles wv*7..wv*7+6
// over pre-pool pixels [2][224] of pooled row py.
__global__ __launch_bounds__(256) void
conv1_mfma(const ushort* __restrict__ x4,    // [128,226,226,4] bf16
           const ushort* __restrict__ wfrag, // [2][64][8] bf16
           const float* __restrict__ bias,   // [16]
           ushort* __restrict__ h1p) {       // [128,114,114,16] bf16
    const int py = blockIdx.x;               // pooled row 0..111
    const int b  = blockIdx.z;
    const int wv = threadIdx.x >> 6, l = threadIdx.x & 63;
    const int lhi = l >> 4, llo = l & 15;

    __shared__ float lds[2][224][17];

    short8 wf[2];
#pragma unroll
    for (int c = 0; c < 2; ++c)
        wf[c] = *(const short8*)&wfrag[(c * 64 + l) * 8];

    f32x4 acc[7];
#pragma unroll
    for (int i = 0; i < 7; ++i) acc[i] = (f32x4){0.f, 0.f, 0.f, 0.f};

#pragma unroll
    for (int i = 0; i < 7; ++i) {
        const int mt = wv * 7 + i;
        const int p0 = mt * 16 + llo;              // A-row pixel for this lane
        const int pr = (p0 >= 224) ? 1 : 0;
        const int px = p0 - 224 * pr;
        const size_t pixbase = ((size_t)(b * 226 + 2 * py + pr)) * 226 + px;
#pragma unroll
        for (int c = 0; c < 2; ++c) {
            const int cc = c * 4 + lhi;            // chunk id 0..7
            const int ky = cc >> 1, half = cc & 1;
            short8 a = {};
            if (ky < 3) {
                const ushort* ap = &x4[(pixbase + ky * 226 + 2 * half) * 4];
                if (half == 0) {
                    a = (short8)(*(const short8u*)ap);
                } else {
                    short4v lo = *(const short4v*)ap;
                    a[0] = lo[0]; a[1] = lo[1]; a[2] = lo[2]; a[3] = lo[3];
                }
            }
            acc[i] = __builtin_amdgcn_mfma_f32_16x16x32_bf16(a, wf[c], acc[i], 0, 0, 0);
        }
    }

    // D: pixel = mt*16 + lhi*4 + j, co = llo
#pragma unroll
    for (int i = 0; i < 7; ++i) {
        const int pbase = (wv * 7 + i) * 16 + lhi * 4;
        const int pr = (pbase >= 224) ? 1 : 0;
        const int pp = pbase - 224 * pr;
#pragma unroll
        for (int j = 0; j < 4; ++j)
            lds[pr][pp + j][llo] = acc[i][j];
    }
    __syncthreads();

    // pool 2x2 + bias + relu -> h1p interior (co-fastest, fully coalesced)
#pragma unroll
    for (int i = 0; i < 7; ++i) {
        int o = threadIdx.x + i * 256;       // 0..1791 = 112 px * 16 co
        int px = o >> 4, co = o & 15;
        float v = fmaxf(fmaxf(lds[0][2 * px][co], lds[0][2 * px + 1][co]),
                        fmaxf(lds[1][2 * px][co], lds[1][2 * px + 1][co]));
        v = fmaxf(v + bias[co], 0.f);
        h1p[(((size_t)b * 114 + 1 + py) * 114 + (1 + px)) * 16 + co] = f2bf(v);
    }
}

// ---------------- conv2: MFMA im2col GEMM, pooled, padded-NHWC bf16 -------------
__global__ __launch_bounds__(256) void
conv2_mfma(const ushort* __restrict__ h1p,   // [128,114,114,16] bf16
           const ushort* __restrict__ wfrag, // [5][2][64][8] bf16
           const float* __restrict__ bias,   // [32]
           ushort* __restrict__ h2p) {       // [128,58,58,32] bf16
    const int py = blockIdx.x;               // pooled row 0..55
    const int b  = blockIdx.z;
    const int wv = threadIdx.x >> 6, l = threadIdx.x & 63;
    const int r = wv >> 1, n = wv & 1;
    const int y = 2 * py + r;                // pre-pool row 0..111
    const int lhi = l >> 4, llo = l & 15;

    __shared__ float lds[2][112][33];

    short8 wf[5];
#pragma unroll
    for (int c = 0; c < 5; ++c)
        wf[c] = *(const short8*)&wfrag[(((c * 2 + n) * 64) + l) * 8];

    int base_el[5];  bool vld[5];
#pragma unroll
    for (int c = 0; c < 5; ++c) {
        int cc = c * 4 + lhi;               // 8-elem chunk id, 0..19
        int dy = cc / 6, off = (cc % 6) * 8;
        vld[c] = (cc < 18);
        base_el[c] = (((b * 114 + y + dy) * 114) * 16) + off;
    }

    f32x4 acc[7];
#pragma unroll
    for (int m = 0; m < 7; ++m) acc[m] = (f32x4){0.f, 0.f, 0.f, 0.f};

#pragma unroll
    for (int m = 0; m < 7; ++m) {
        const int xe = (m * 16 + llo) * 16;
#pragma unroll
        for (int c = 0; c < 5; ++c) {
            short8 a = {};
            if (vld[c]) a = *(const short8*)&h1p[base_el[c] + xe];
            acc[m] = __builtin_amdgcn_mfma_f32_16x16x32_bf16(a, wf[c], acc[m], 0, 0, 0);
        }
    }

#pragma unroll
    for (int m = 0; m < 7; ++m)
#pragma unroll
        for (int j = 0; j < 4; ++j)
            lds[r][m * 16 + lhi * 4 + j][n * 16 + llo] = acc[m][j];
    __syncthreads();

#pragma unroll
    for (int i = 0; i < 7; ++i) {
        int o = threadIdx.x + i * 256;       // 0..1791
        int px = o >> 5, co = o & 31;
        float v = fmaxf(fmaxf(lds[0][2 * px][co], lds[0][2 * px + 1][co]),
                        fmaxf(lds[1][2 * px][co], lds[1][2 * px + 1][co]));
        v = fmaxf(v + bias[co], 0.f);
        h2p[(((size_t)b * 58 + 1 + py) * 58 + 1 + px) * 32 + co] = f2bf(v);
    }
}

// ---------------- conv3: MFMA im2col GEMM, pooled, NCHW fp32 out ----------------
__global__ __launch_bounds__(256) void
conv3_mfma(const ushort* __restrict__ h2p,   // [128,58,58,32] bf16
           const ushort* __restrict__ wfrag, // [9][4][64][8] bf16
           const float* __restrict__ bias,   // [64]
           float* __restrict__ h3) {         // [128,64,28,28] fp32
    const int py = blockIdx.x;               // pooled row 0..27
    const int b  = blockIdx.z;
    const int n = threadIdx.x >> 6, l = threadIdx.x & 63;
    const int lhi = l >> 4, llo = l & 15;

    __shared__ float lds[112][65];

    short8 wf[9];
#pragma unroll
    for (int c = 0; c < 9; ++c)
        wf[c] = *(const short8*)&wfrag[(((c * 4 + n) * 64) + l) * 8];

    int rowbase[9];
#pragma unroll
    for (int c = 0; c < 9; ++c) {
        int cc = c * 4 + lhi;               // 0..35
        int dy = cc / 12, off = (cc % 12) * 8;
        rowbase[c] = (((b * 58 + 2 * py + dy) * 58) * 32) + off;
    }

    f32x4 acc[7];
#pragma unroll
    for (int m = 0; m < 7; ++m) acc[m] = (f32x4){0.f, 0.f, 0.f, 0.f};

#pragma unroll
    for (int m = 0; m < 7; ++m) {
        const int p = m * 16 + llo;          // pixel 0..111 (row-major 2x56)
        const int prow = (p >= 56) ? 1 : 0;
        const int add = prow * (58 * 32) + (p - 56 * prow) * 32;
#pragma unroll
        for (int c = 0; c < 9; ++c) {
            short8 a = *(const short8*)&h2p[rowbase[c] + add];
            acc[m] = __builtin_amdgcn_mfma_f32_16x16x32_bf16(a, wf[c], acc[m], 0, 0, 0);
        }
    }

#pragma unroll
    for (int m = 0; m < 7; ++m)
#pragma unroll
        for (int j = 0; j < 4; ++j)
            lds[m * 16 + lhi * 4 + j][n * 16 + llo] = acc[m][j];
    __syncthreads();

#pragma unroll
    for (int i = 0; i < 7; ++i) {
        int o = threadIdx.x + i * 256;       // 0..1791
        int px = o % 28, co = o / 28;
        float v = fmaxf(fmaxf(lds[2 * px][co], lds[2 * px + 1][co]),
                        fmaxf(lds[56 + 2 * px][co], lds[57 + 2 * px][co]));
        v = fmaxf(v + bias[co], 0.f);
        h3[(((size_t)b * 64 + co) * 28 + py) * 28 + px] = v;
    }
}

// ---------------- FC1 stage A/B and FC2: unchanged (known good) -----------------
__global__ void fc1_stageA(const float* __restrict__ act,
                           const float* __restrict__ wf,
                           float* __restrict__ partials) {
    const int K = 50176, KSPLIT = 3136, KC = 64;
    const int bt = blockIdx.x * 32, ct = blockIdx.y * 32, ks = blockIdx.z;
    const int tx = threadIdx.x & 15, ty = threadIdx.x >> 4;

    __shared__ __align__(16) float A[32][68];
    __shared__ __align__(16) float Wl[32][68];

    float a00 = 0.f, a01 = 0.f, a10 = 0.f, a11 = 0.f;
    const int k_base = ks * KSPLIT;
    for (int k0 = k_base; k0 < k_base + KSPLIT; k0 += KC) {
        __syncthreads();
#pragma unroll
        for (int j = 0; j < 2; ++j) {
            const int s = threadIdx.x + j * 256;
            const int r = s >> 4, c4 = (s & 15) * 4;
            const float4 av = *(const float4*)&act[(size_t)(bt + r) * K + k0 + c4];
            *(float4*)&A[r][c4] = av;
            float4 wvv = *(const float4*)&wf[(size_t)(ct + r) * K + k0 + c4];
            wvv.x = sgn(wvv.x); wvv.y = sgn(wvv.y); wvv.z = sgn(wvv.z); wvv.w = sgn(wvv.w);
            *(float4*)&Wl[r][c4] = wvv;
        }
        __syncthreads();
#pragma unroll
        for (int k4 = 0; k4 < 16; ++k4) {
            const float4 x0 = *(const float4*)&A[ty][k4 * 4];
            const float4 x1 = *(const float4*)&A[ty + 16][k4 * 4];
            const float4 w0 = *(const float4*)&Wl[tx][k4 * 4];
            const float4 w1 = *(const float4*)&Wl[tx + 16][k4 * 4];
            a00 = fmaf(x0.x, w0.x, fmaf(x0.y, w0.y, fmaf(x0.z, w0.z, fmaf(x0.w, w0.w, a00))));
            a01 = fmaf(x0.x, w1.x, fmaf(x0.y, w1.y, fmaf(x0.z, w1.z, fmaf(x0.w, w1.w, a01))));
            a10 = fmaf(x1.x, w0.x, fmaf(x1.y, w0.y, fmaf(x1.z, w0.z, fmaf(x1.w, w0.w, a10))));
            a11 = fmaf(x1.x, w1.x, fmaf(x1.y, w1.y, fmaf(x1.z, w1.z, fmaf(x1.w, w1.w, a11))));
        }
    }
    float* pb = partials + (size_t)ks * 128 * 128;
    pb[(bt + ty)      * 128 + ct + tx]      = a00;
    pb[(bt + ty)      * 128 + ct + tx + 16] = a01;
    pb[(bt + ty + 16) * 128 + ct + tx]      = a10;
    pb[(bt + ty + 16) * 128 + ct + tx + 16] = a11;
}

__global__ void fc1_stageB(const float* __restrict__ partials,
                           const float* __restrict__ bf,
                           float* __restrict__ f1) {
    const int o = blockIdx.x * 256 + threadIdx.x;
    float acc = 0.f;
#pragma unroll
    for (int ks = 0; ks < 16; ++ks) acc += partials[(size_t)ks * 16384 + o];
    f1[o] = fmaxf(acc + bf[o & 127], 0.f);
}

__global__ void fc2_kernel(const float* __restrict__ act,
                           const float* __restrict__ wf,
                           const float* __restrict__ bf,
                           float* __restrict__ out) {
    const int o = blockIdx.x * 256 + threadIdx.x;
    if (o >= 128 * 1000) return;
    const int b = o / 1000, co = o % 1000;
    const float* a  = act + b * 128;
    const float* wr = wf + co * 128;
    float acc = 0.f;
#pragma unroll 8
    for (int k = 0; k < 128; ++k)
        acc = fmaf(a[k], sgn(wr[k]), acc);
    out[o] = acc + bf[co];
}

extern "C" void kernel_launch(void* const* d_in, const int* in_sizes, int n_in,
                              void* d_out, int out_size, void* d_ws, size_t ws_size,
                              hipStream_t stream) {
    const float* x   = (const float*)d_in[0];
    const float* w1  = (const float*)d_in[1];
    const float* b1  = (const float*)d_in[2];
    const float* w2  = (const float*)d_in[3];
    const float* b2  = (const float*)d_in[4];
    const float* w3  = (const float*)d_in[5];
    const float* b3  = (const float*)d_in[6];
    const float* wf1 = (const float*)d_in[7];
    const float* bf1 = (const float*)d_in[8];
    const float* wf2 = (const float*)d_in[9];
    const float* bf2 = (const float*)d_in[10];

    // ws layout (peak 133.1 MB):
    //   h1p bf16 [128,114,114,16] @ 0            (53,231,616)
    //   x4  bf16 [128,226,226,4]  @ 53,231,616   (52,276,224)  dead after conv1
    //   h2p bf16 [128,58,58,32]   @ 105,507,840  (27,557,888)
    //   wf1frag @ 133,065,728 (2,048); wf2frag @ 133,067,776 (10,240);
    //   wf3frag @ 133,078,016 (36,864)
    //   h3 fp32 [128,64,28,28]    @ 53,231,616   (25,690,112)  reuses dead x4
    //   pa fp32 [16][16384]       @ 78,921,728   ( 1,048,576)
    //   f1 fp32 [128,128]         @ 79,970,304   (    65,536)
    char* ws = (char*)d_ws;
    ushort* h1p = (ushort*)ws;
    ushort* x4  = (ushort*)(ws + 53231616u);
    ushort* h2p = (ushort*)(ws + 105507840u);
    ushort* wf1frag = (ushort*)(ws + 133065728u);
    ushort* wf2frag = (ushort*)(ws + 133067776u);
    ushort* wf3frag = (ushort*)(ws + 133078016u);
    float*  h3  = (float*)(ws + 53231616u);
    float*  pa  = (float*)(ws + 78921728u);
    float*  f1  = (float*)(ws + 79970304u);

    pad_zero<<<7265, 256, 0, stream>>>(h1p, h2p);
    wfrag_prep<<<96, 256, 0, stream>>>(w2, w3, w1, wf2frag, wf3frag, wf1frag);
    x4_prep<<<25538, 256, 0, stream>>>(x, x4);
    conv1_mfma<<<dim3(112, 1, 128), 256, 0, stream>>>(x4, wf1frag, b1, h1p);
    conv2_mfma<<<dim3(56, 1, 128), 256, 0, stream>>>(h1p, wf2frag, b2, h2p);
    conv3_mfma<<<dim3(28, 1, 128), 256, 0, stream>>>(h2p, wf3frag, b3, h3);
    fc1_stageA<<<dim3(4, 4, 16), 256, 0, stream>>>(h3, wf1, pa);
    fc1_stageB<<<64, 256, 0, stream>>>(pa, bf1, f1);
    fc2_kernel<<<500, 256, 0, stream>>>(f1, wf2, bf2, (float*)d_out);
}

// Round 7
// 254.252 us; speedup vs baseline: 19.7676x; 1.1795x over previous
//
#include <hip/hip_runtime.h>

typedef __attribute__((ext_vector_type(8))) short short8;
typedef __attribute__((ext_vector_type(8), aligned(8))) short short8u;  // 8B-aligned 16B load
typedef __attribute__((ext_vector_type(4))) short short4v;
typedef __attribute__((ext_vector_type(4))) float f32x4;
typedef unsigned short ushort;
typedef unsigned int uint;

static __device__ __forceinline__ float sgn(float v) {
    return (v > 0.f) ? 1.f : ((v < 0.f) ? -1.f : 0.f);
}
static __device__ __forceinline__ ushort f2bf(float f) {
    uint u = __builtin_bit_cast(uint, f);
    u += 0x7fffu + ((u >> 16) & 1u);   // RNE
    return (ushort)(u >> 16);
}
static __device__ __forceinline__ ushort sgn2bf(float v) {
    return (v > 0.f) ? (ushort)0x3F80 : ((v < 0.f) ? (ushort)0xBF80 : (ushort)0);
}

// ---------------- pad-zero: zero the halo borders of h1p and h2p ----------------
__global__ void pad_zero(ushort* __restrict__ h1p, ushort* __restrict__ h2p) {
    int t = blockIdx.x * 256 + threadIdx.x;
    if (t < 925696) {                       // h1p: 128 b x 452 cells x 16 ch
        int b = t / 7232, r = t % 7232;
        int cell = r >> 4, ch = r & 15;
        int y, x;
        if (cell < 114)      { y = 0;   x = cell; }
        else if (cell < 228) { y = 113; x = cell - 114; }
        else { int s = cell - 228; y = 1 + (s >> 1); x = (s & 1) ? 113 : 0; }
        h1p[((b * 114 + y) * 114 + x) * 16 + ch] = 0;
    } else {
        t -= 925696;
        if (t >= 933888) return;            // h2p: 128 b x 228 cells x 32 ch
        int b = t / 7296, r = t % 7296;
        int cell = r >> 5, ch = r & 31;
        int y, x;
        if (cell < 58)       { y = 0;  x = cell; }
        else if (cell < 116) { y = 57; x = cell - 58; }
        else { int s = cell - 116; y = 1 + (s >> 1); x = (s & 1) ? 57 : 0; }
        h2p[((b * 58 + y) * 58 + x) * 32 + ch] = 0;
    }
}

// ---------------- x4_prep: x NCHW fp32 -> padded NHWC-4ch bf16 ------------------
__global__ void x4_prep(const float* __restrict__ x,   // [128,3,224,224]
                        ushort* __restrict__ x4) {
    int t = blockIdx.x * 256 + threadIdx.x;
    if (t >= 128 * 51076) return;
    int b = t / 51076, pix = t % 51076;
    int Y = pix / 226, X = pix % 226;
    ushort pk[4] = {0, 0, 0, 0};
    if (Y >= 1 && Y <= 224 && X >= 1 && X <= 224) {
        const float* xb = x + ((size_t)b * 3) * 50176 + (Y - 1) * 224 + (X - 1);
        pk[0] = f2bf(xb[0]);
        pk[1] = f2bf(xb[50176]);
        pk[2] = f2bf(xb[100352]);
    }
    *(short4v*)&x4[(size_t)t * 4] = *(const short4v*)pk;
}

// ---------------- weight-fragment prep (sgn -> bf16, MFMA fragment order) -------
__global__ void wfrag_prep(const float* __restrict__ w2, const float* __restrict__ w3,
                           const float* __restrict__ w1,
                           ushort* __restrict__ f2, ushort* __restrict__ f3,
                           ushort* __restrict__ f1) {
    int t = blockIdx.x * 256 + threadIdx.x;
    if (t < 5120) {
        int j = t & 7, l = (t >> 3) & 63, nc = t >> 9;  // nc = c*2 + n
        int n = nc & 1, c = nc >> 1;
        int k = c * 32 + ((l >> 4) << 3) + j;
        ushort v = 0;
        if (k < 144) {
            int ky = k / 48, rem = k % 48, kx = rem >> 4, ci = rem & 15;
            int co = n * 16 + (l & 15);
            v = sgn2bf(w2[((co * 16 + ci) * 3 + ky) * 3 + kx]);
        }
        f2[t] = v;
    } else if (t < 23552) {
        int t2 = t - 5120;
        int j = t2 & 7, l = (t2 >> 3) & 63, nc = t2 >> 9;  // nc = c*4 + n
        int n = nc & 3, c = nc >> 2;
        int k = c * 32 + ((l >> 4) << 3) + j;               // < 288
        int ky = k / 96, rem = k % 96, kx = rem >> 5, ci = rem & 31;
        int co = n * 16 + (l & 15);
        f3[t2] = sgn2bf(w3[((co * 32 + ci) * 3 + ky) * 3 + kx]);
    } else {
        int t1 = t - 23552;
        if (t1 >= 1024) return;
        int j = t1 & 7, l = (t1 >> 3) & 63, c = t1 >> 9;    // c = 0,1
        int k = c * 32 + ((l >> 4) << 3) + j;               // 0..63
        int ky = k >> 4, kx = (k >> 2) & 3, ci = k & 3;
        ushort v = 0;
        if (ky < 3 && kx < 3 && ci < 3) {
            int co = l & 15;
            v = sgn2bf(w1[((co * 3 + ci) * 3 + ky) * 3 + kx]);
        }
        f1[t1] = v;
    }
}

// ---------------- wf1_prep: wf1 fp32 [128][50176] -> sign bf16 ------------------
__global__ void wf1_prep(const float* __restrict__ wf1, ushort* __restrict__ wsg) {
    int t = blockIdx.x * 256 + threadIdx.x;          // one float4 per thread
    if (t >= 128 * 50176 / 4) return;
    const float4 v = *(const float4*)&wf1[(size_t)t * 4];
    ushort pk[4] = {sgn2bf(v.x), sgn2bf(v.y), sgn2bf(v.z), sgn2bf(v.w)};
    *(short4v*)&wsg[(size_t)t * 4] = *(const short4v*)pk;
}

// ---------------- conv1: MFMA im2col GEMM (K=27 pad 64), pooled, NHWC bf16 ------
__global__ __launch_bounds__(256) void
conv1_mfma(const ushort* __restrict__ x4,    // [128,226,226,4] bf16
           const ushort* __restrict__ wfrag, // [2][64][8] bf16
           const float* __restrict__ bias,   // [16]
           ushort* __restrict__ h1p) {       // [128,114,114,16] bf16
    const int py = blockIdx.x;               // pooled row 0..111
    const int b  = blockIdx.z;
    const int wv = threadIdx.x >> 6, l = threadIdx.x & 63;
    const int lhi = l >> 4, llo = l & 15;

    __shared__ float lds[2][224][17];

    short8 wf[2];
#pragma unroll
    for (int c = 0; c < 2; ++c)
        wf[c] = *(const short8*)&wfrag[(c * 64 + l) * 8];

    f32x4 acc[7];
#pragma unroll
    for (int i = 0; i < 7; ++i) acc[i] = (f32x4){0.f, 0.f, 0.f, 0.f};

#pragma unroll
    for (int i = 0; i < 7; ++i) {
        const int mt = wv * 7 + i;
        const int p0 = mt * 16 + llo;
        const int pr = (p0 >= 224) ? 1 : 0;
        const int px = p0 - 224 * pr;
        const size_t pixbase = ((size_t)(b * 226 + 2 * py + pr)) * 226 + px;
#pragma unroll
        for (int c = 0; c < 2; ++c) {
            const int cc = c * 4 + lhi;
            const int ky = cc >> 1, half = cc & 1;
            short8 a = {};
            if (ky < 3) {
                const ushort* ap = &x4[(pixbase + ky * 226 + 2 * half) * 4];
                if (half == 0) {
                    a = (short8)(*(const short8u*)ap);
                } else {
                    short4v lo = *(const short4v*)ap;
                    a[0] = lo[0]; a[1] = lo[1]; a[2] = lo[2]; a[3] = lo[3];
                }
            }
            acc[i] = __builtin_amdgcn_mfma_f32_16x16x32_bf16(a, wf[c], acc[i], 0, 0, 0);
        }
    }

#pragma unroll
    for (int i = 0; i < 7; ++i) {
        const int pbase = (wv * 7 + i) * 16 + lhi * 4;
        const int pr = (pbase >= 224) ? 1 : 0;
        const int pp = pbase - 224 * pr;
#pragma unroll
        for (int j = 0; j < 4; ++j)
            lds[pr][pp + j][llo] = acc[i][j];
    }
    __syncthreads();

#pragma unroll
    for (int i = 0; i < 7; ++i) {
        int o = threadIdx.x + i * 256;       // 0..1791 = 112 px * 16 co
        int px = o >> 4, co = o & 15;
        float v = fmaxf(fmaxf(lds[0][2 * px][co], lds[0][2 * px + 1][co]),
                        fmaxf(lds[1][2 * px][co], lds[1][2 * px + 1][co]));
        v = fmaxf(v + bias[co], 0.f);
        h1p[(((size_t)b * 114 + 1 + py) * 114 + (1 + px)) * 16 + co] = f2bf(v);
    }
}

// ---------------- conv2: MFMA im2col GEMM, pooled, padded-NHWC bf16 -------------
__global__ __launch_bounds__(256) void
conv2_mfma(const ushort* __restrict__ h1p,   // [128,114,114,16] bf16
           const ushort* __restrict__ wfrag, // [5][2][64][8] bf16
           const float* __restrict__ bias,   // [32]
           ushort* __restrict__ h2p) {       // [128,58,58,32] bf16
    const int py = blockIdx.x;               // pooled row 0..55
    const int b  = blockIdx.z;
    const int wv = threadIdx.x >> 6, l = threadIdx.x & 63;
    const int r = wv >> 1, n = wv & 1;
    const int y = 2 * py + r;
    const int lhi = l >> 4, llo = l & 15;

    __shared__ float lds[2][112][33];

    short8 wf[5];
#pragma unroll
    for (int c = 0; c < 5; ++c)
        wf[c] = *(const short8*)&wfrag[(((c * 2 + n) * 64) + l) * 8];

    int base_el[5];  bool vld[5];
#pragma unroll
    for (int c = 0; c < 5; ++c) {
        int cc = c * 4 + lhi;
        int dy = cc / 6, off = (cc % 6) * 8;
        vld[c] = (cc < 18);
        base_el[c] = (((b * 114 + y + dy) * 114) * 16) + off;
    }

    f32x4 acc[7];
#pragma unroll
    for (int m = 0; m < 7; ++m) acc[m] = (f32x4){0.f, 0.f, 0.f, 0.f};

#pragma unroll
    for (int m = 0; m < 7; ++m) {
        const int xe = (m * 16 + llo) * 16;
#pragma unroll
        for (int c = 0; c < 5; ++c) {
            short8 a = {};
            if (vld[c]) a = *(const short8*)&h1p[base_el[c] + xe];
            acc[m] = __builtin_amdgcn_mfma_f32_16x16x32_bf16(a, wf[c], acc[m], 0, 0, 0);
        }
    }

#pragma unroll
    for (int m = 0; m < 7; ++m)
#pragma unroll
        for (int j = 0; j < 4; ++j)
            lds[r][m * 16 + lhi * 4 + j][n * 16 + llo] = acc[m][j];
    __syncthreads();

#pragma unroll
    for (int i = 0; i < 7; ++i) {
        int o = threadIdx.x + i * 256;
        int px = o >> 5, co = o & 31;
        float v = fmaxf(fmaxf(lds[0][2 * px][co], lds[0][2 * px + 1][co]),
                        fmaxf(lds[1][2 * px][co], lds[1][2 * px + 1][co]));
        v = fmaxf(v + bias[co], 0.f);
        h2p[(((size_t)b * 58 + 1 + py) * 58 + 1 + px) * 32 + co] = f2bf(v);
    }
}

// ---------------- conv3: MFMA im2col GEMM, pooled, bf16 [128][50176] out --------
__global__ __launch_bounds__(256) void
conv3_mfma(const ushort* __restrict__ h2p,   // [128,58,58,32] bf16
           const ushort* __restrict__ wfrag, // [9][4][64][8] bf16
           const float* __restrict__ bias,   // [64]
           ushort* __restrict__ h3b) {       // [128][50176] bf16 (NCHW flatten)
    const int py = blockIdx.x;               // pooled row 0..27
    const int b  = blockIdx.z;
    const int n = threadIdx.x >> 6, l = threadIdx.x & 63;
    const int lhi = l >> 4, llo = l & 15;

    __shared__ float lds[112][65];

    short8 wf[9];
#pragma unroll
    for (int c = 0; c < 9; ++c)
        wf[c] = *(const short8*)&wfrag[(((c * 4 + n) * 64) + l) * 8];

    int rowbase[9];
#pragma unroll
    for (int c = 0; c < 9; ++c) {
        int cc = c * 4 + lhi;
        int dy = cc / 12, off = (cc % 12) * 8;
        rowbase[c] = (((b * 58 + 2 * py + dy) * 58) * 32) + off;
    }

    f32x4 acc[7];
#pragma unroll
    for (int m = 0; m < 7; ++m) acc[m] = (f32x4){0.f, 0.f, 0.f, 0.f};

#pragma unroll
    for (int m = 0; m < 7; ++m) {
        const int p = m * 16 + llo;
        const int prow = (p >= 56) ? 1 : 0;
        const int add = prow * (58 * 32) + (p - 56 * prow) * 32;
#pragma unroll
        for (int c = 0; c < 9; ++c) {
            short8 a = *(const short8*)&h2p[rowbase[c] + add];
            acc[m] = __builtin_amdgcn_mfma_f32_16x16x32_bf16(a, wf[c], acc[m], 0, 0, 0);
        }
    }

#pragma unroll
    for (int m = 0; m < 7; ++m)
#pragma unroll
        for (int j = 0; j < 4; ++j)
            lds[m * 16 + lhi * 4 + j][n * 16 + llo] = acc[m][j];
    __syncthreads();

    // h3b[b][co*784 + py*28 + px]
#pragma unroll
    for (int i = 0; i < 7; ++i) {
        int o = threadIdx.x + i * 256;       // 0..1791
        int px = o % 28, co = o / 28;
        float v = fmaxf(fmaxf(lds[2 * px][co], lds[2 * px + 1][co]),
                        fmaxf(lds[56 + 2 * px][co], lds[57 + 2 * px][co]));
        v = fmaxf(v + bias[co], 0.f);
        h3b[(size_t)b * 50176 + co * 784 + py * 28 + px] = f2bf(v);
    }
}

// ---------------- FC1 stage A: bf16 MFMA split-K GEMM ---------------------------
// M=128(b) x N=128(co) x K=50176. grid (4 bt, 4 ct, 49 ks), block 256 = 4 waves.
// Each wave: K-subrange of 256 (8 k-steps of 32), 2x2 MFMA fragments (32b x 32co).
// Lanes (llo, lhi): lhi walks 4 consecutive 16B k-chunks of the same row -> full
// 64B line utilization despite row-strided access.
__global__ __launch_bounds__(256) void
fc1_mfmaA(const ushort* __restrict__ actb,  // [128][50176] bf16
          const ushort* __restrict__ wsg,   // [128][50176] bf16 (sign)
          float* __restrict__ partials) {   // [49][128][128]
    const int K = 50176;
    const int bt = blockIdx.x * 32, ct = blockIdx.y * 32, ks = blockIdx.z;
    const int wv = threadIdx.x >> 6, l = threadIdx.x & 63;
    const int lhi = l >> 4, llo = l & 15;

    __shared__ float lds[4][32][33];

    f32x4 acc[2][2];
#pragma unroll
    for (int i = 0; i < 2; ++i)
#pragma unroll
        for (int j = 0; j < 2; ++j) acc[i][j] = (f32x4){0.f, 0.f, 0.f, 0.f};

    const int kw = ks * 1024 + wv * 256 + lhi * 8;
    const ushort* a0p = actb + (size_t)(bt + llo)      * K + kw;
    const ushort* a1p = actb + (size_t)(bt + llo + 16) * K + kw;
    const ushort* b0p = wsg  + (size_t)(ct + llo)      * K + kw;
    const ushort* b1p = wsg  + (size_t)(ct + llo + 16) * K + kw;

#pragma unroll
    for (int s = 0; s < 8; ++s) {
        const int off = s * 32;
        const short8 a0 = *(const short8*)(a0p + off);
        const short8 a1 = *(const short8*)(a1p + off);
        const short8 b0 = *(const short8*)(b0p + off);
        const short8 b1 = *(const short8*)(b1p + off);
        acc[0][0] = __builtin_amdgcn_mfma_f32_16x16x32_bf16(a0, b0, acc[0][0], 0, 0, 0);
        acc[0][1] = __builtin_amdgcn_mfma_f32_16x16x32_bf16(a0, b1, acc[0][1], 0, 0, 0);
        acc[1][0] = __builtin_amdgcn_mfma_f32_16x16x32_bf16(a1, b0, acc[1][0], 0, 0, 0);
        acc[1][1] = __builtin_amdgcn_mfma_f32_16x16x32_bf16(a1, b1, acc[1][1], 0, 0, 0);
    }

    // D: row m = i*16 + lhi*4 + j, col n = jj*16 + llo
#pragma unroll
    for (int i = 0; i < 2; ++i)
#pragma unroll
        for (int jj = 0; jj < 2; ++jj)
#pragma unroll
            for (int j = 0; j < 4; ++j)
                lds[wv][i * 16 + lhi * 4 + j][jj * 16 + llo] = acc[i][jj][j];
    __syncthreads();

    float* pb = partials + (size_t)ks * 16384;
#pragma unroll
    for (int u = 0; u < 4; ++u) {
        int idx = threadIdx.x + u * 256;     // 0..1023
        int m = idx >> 5, n = idx & 31;
        float v = lds[0][m][n] + lds[1][m][n] + lds[2][m][n] + lds[3][m][n];
        pb[(bt + m) * 128 + ct + n] = v;
    }
}

// ---------------- FC1 stage B: reduce 49 partials + bias + relu -----------------
__global__ void fc1_stageB(const float* __restrict__ partials,
                           const float* __restrict__ bf,
                           float* __restrict__ f1) {
    const int o = blockIdx.x * 256 + threadIdx.x;  // 0..16383
    float acc = 0.f;
    for (int ks = 0; ks < 49; ++ks) acc += partials[(size_t)ks * 16384 + o];
    f1[o] = fmaxf(acc + bf[o & 127], 0.f);
}

// ---------------- FC2 ------------------------------------------------------------
__global__ void fc2_kernel(const float* __restrict__ act,
                           const float* __restrict__ wf,
                           const float* __restrict__ bf,
                           float* __restrict__ out) {
    const int o = blockIdx.x * 256 + threadIdx.x;
    if (o >= 128 * 1000) return;
    const int b = o / 1000, co = o % 1000;
    const float* a  = act + b * 128;
    const float* wr = wf + co * 128;
    float acc = 0.f;
#pragma unroll 8
    for (int k = 0; k < 128; ++k)
        acc = fmaf(a[k], sgn(wr[k]), acc);
    out[o] = acc + bf[co];
}

extern "C" void kernel_launch(void* const* d_in, const int* in_sizes, int n_in,
                              void* d_out, int out_size, void* d_ws, size_t ws_size,
                              hipStream_t stream) {
    const float* x   = (const float*)d_in[0];
    const float* w1  = (const float*)d_in[1];
    const float* b1  = (const float*)d_in[2];
    const float* w2  = (const float*)d_in[3];
    const float* b2  = (const float*)d_in[4];
    const float* w3  = (const float*)d_in[5];
    const float* b3  = (const float*)d_in[6];
    const float* wf1 = (const float*)d_in[7];
    const float* bf1 = (const float*)d_in[8];
    const float* wf2 = (const float*)d_in[9];
    const float* bf2 = (const float*)d_in[10];

    // ws layout (peak 133.1 MB):
    //   h1p bf16 [128,114,114,16] @ 0            (53,231,616)
    //   x4  bf16 [128,226,226,4]  @ 53,231,616   (52,276,224)  dead after conv1
    //     overlaid on dead x4:
    //     h3b  bf16 [128][50176]  @ 53,231,616   (12,845,056)  written by conv3
    //     wsg1 bf16 [128][50176]  @ 66,076,672   (12,845,056)  written by wf1_prep
    //     pa   fp32 [49][16384]   @ 78,921,728   ( 3,211,264)
    //     f1   fp32 [128,128]     @ 82,132,992   (    65,536)
    //   h2p bf16 [128,58,58,32]   @ 105,507,840  (27,557,888)
    //   wf1frag @ 133,065,728 (2,048); wf2frag @ 133,067,776 (10,240);
    //   wf3frag @ 133,078,016 (36,864)
    char* ws = (char*)d_ws;
    ushort* h1p  = (ushort*)ws;
    ushort* x4   = (ushort*)(ws + 53231616u);
    ushort* h3b  = (ushort*)(ws + 53231616u);
    ushort* wsg1 = (ushort*)(ws + 66076672u);
    float*  pa   = (float*) (ws + 78921728u);
    float*  f1   = (float*) (ws + 82132992u);
    ushort* h2p  = (ushort*)(ws + 105507840u);
    ushort* wf1frag = (ushort*)(ws + 133065728u);
    ushort* wf2frag = (ushort*)(ws + 133067776u);
    ushort* wf3frag = (ushort*)(ws + 133078016u);

    pad_zero<<<7265, 256, 0, stream>>>(h1p, h2p);
    wfrag_prep<<<96, 256, 0, stream>>>(w2, w3, w1, wf2frag, wf3frag, wf1frag);
    x4_prep<<<25538, 256, 0, stream>>>(x, x4);
    conv1_mfma<<<dim3(112, 1, 128), 256, 0, stream>>>(x4, wf1frag, b1, h1p);
    // x4 now dead; regions overlaying it may be written from here on
    wf1_prep<<<6272, 256, 0, stream>>>(wf1, wsg1);
    conv2_mfma<<<dim3(56, 1, 128), 256, 0, stream>>>(h1p, wf2frag, b2, h2p);
    conv3_mfma<<<dim3(28, 1, 128), 256, 0, stream>>>(h2p, wf3frag, b3, h3b);
    fc1_mfmaA<<<dim3(4, 4, 49), 256, 0, stream>>>(h3b, wsg1, pa);
    fc1_stageB<<<64, 256, 0, stream>>>(pa, bf1, f1);
    fc2_kernel<<<500, 256, 0, stream>>>(f1, wf2, bf2, (float*)d_out);
}

// Round 8
// 221.485 us; speedup vs baseline: 22.6921x; 1.1479x over previous
//
#include <hip/hip_runtime.h>

typedef __attribute__((ext_vector_type(8))) short short8;
typedef __attribute__((ext_vector_type(8), aligned(8))) short short8u;  // 8B-aligned 16B load
typedef __attribute__((ext_vector_type(4))) short short4v;
typedef __attribute__((ext_vector_type(4))) float f32x4;
typedef unsigned short ushort;
typedef unsigned int uint;

static __device__ __forceinline__ float sgn(float v) {
    return (v > 0.f) ? 1.f : ((v < 0.f) ? -1.f : 0.f);
}
static __device__ __forceinline__ ushort f2bf(float f) {
    uint u = __builtin_bit_cast(uint, f);
    u += 0x7fffu + ((u >> 16) & 1u);   // RNE
    return (ushort)(u >> 16);
}
static __device__ __forceinline__ ushort sgn2bf(float v) {
    return (v > 0.f) ? (ushort)0x3F80 : ((v < 0.f) ? (ushort)0xBF80 : (ushort)0);
}

// ---------------- pad-zero: zero the halo borders of h1p and h2p ----------------
__global__ void pad_zero(ushort* __restrict__ h1p, ushort* __restrict__ h2p) {
    int t = blockIdx.x * 256 + threadIdx.x;
    if (t < 925696) {                       // h1p: 128 b x 452 cells x 16 ch
        int b = t / 7232, r = t % 7232;
        int cell = r >> 4, ch = r & 15;
        int y, x;
        if (cell < 114)      { y = 0;   x = cell; }
        else if (cell < 228) { y = 113; x = cell - 114; }
        else { int s = cell - 228; y = 1 + (s >> 1); x = (s & 1) ? 113 : 0; }
        h1p[((b * 114 + y) * 114 + x) * 16 + ch] = 0;
    } else {
        t -= 925696;
        if (t >= 933888) return;            // h2p: 128 b x 228 cells x 32 ch
        int b = t / 7296, r = t % 7296;
        int cell = r >> 5, ch = r & 31;
        int y, x;
        if (cell < 58)       { y = 0;  x = cell; }
        else if (cell < 116) { y = 57; x = cell - 58; }
        else { int s = cell - 116; y = 1 + (s >> 1); x = (s & 1) ? 57 : 0; }
        h2p[((b * 58 + y) * 58 + x) * 32 + ch] = 0;
    }
}

// ---------------- x4_prep: x NCHW fp32 -> padded NHWC-4ch bf16 ------------------
__global__ void x4_prep(const float* __restrict__ x,   // [128,3,224,224]
                        ushort* __restrict__ x4) {
    int t = blockIdx.x * 256 + threadIdx.x;
    if (t >= 128 * 51076) return;
    int b = t / 51076, pix = t % 51076;
    int Y = pix / 226, X = pix % 226;
    ushort pk[4] = {0, 0, 0, 0};
    if (Y >= 1 && Y <= 224 && X >= 1 && X <= 224) {
        const float* xb = x + ((size_t)b * 3) * 50176 + (Y - 1) * 224 + (X - 1);
        pk[0] = f2bf(xb[0]);
        pk[1] = f2bf(xb[50176]);
        pk[2] = f2bf(xb[100352]);
    }
    *(short4v*)&x4[(size_t)t * 4] = *(const short4v*)pk;
}

// ---------------- weight-fragment prep (sgn -> bf16, MFMA fragment order) -------
__global__ void wfrag_prep(const float* __restrict__ w2, const float* __restrict__ w3,
                           const float* __restrict__ w1,
                           ushort* __restrict__ f2, ushort* __restrict__ f3,
                           ushort* __restrict__ f1) {
    int t = blockIdx.x * 256 + threadIdx.x;
    if (t < 5120) {
        int j = t & 7, l = (t >> 3) & 63, nc = t >> 9;  // nc = c*2 + n
        int n = nc & 1, c = nc >> 1;
        int k = c * 32 + ((l >> 4) << 3) + j;
        ushort v = 0;
        if (k < 144) {
            int ky = k / 48, rem = k % 48, kx = rem >> 4, ci = rem & 15;
            int co = n * 16 + (l & 15);
            v = sgn2bf(w2[((co * 16 + ci) * 3 + ky) * 3 + kx]);
        }
        f2[t] = v;
    } else if (t < 23552) {
        int t2 = t - 5120;
        int j = t2 & 7, l = (t2 >> 3) & 63, nc = t2 >> 9;  // nc = c*4 + n
        int n = nc & 3, c = nc >> 2;
        int k = c * 32 + ((l >> 4) << 3) + j;               // < 288
        int ky = k / 96, rem = k % 96, kx = rem >> 5, ci = rem & 31;
        int co = n * 16 + (l & 15);
        f3[t2] = sgn2bf(w3[((co * 32 + ci) * 3 + ky) * 3 + kx]);
    } else {
        int t1 = t - 23552;
        if (t1 >= 1024) return;
        int j = t1 & 7, l = (t1 >> 3) & 63, c = t1 >> 9;    // c = 0,1
        int k = c * 32 + ((l >> 4) << 3) + j;               // 0..63
        int ky = k >> 4, kx = (k >> 2) & 3, ci = k & 3;
        ushort v = 0;
        if (ky < 3 && kx < 3 && ci < 3) {
            int co = l & 15;
            v = sgn2bf(w1[((co * 3 + ci) * 3 + ky) * 3 + kx]);
        }
        f1[t1] = v;
    }
}

// ---------------- wf1_prep_t: wf1 fp32 [128][50176] -> sign bf16, K-permuted ----
// Output k' = p*64 + co (matches conv3's NHWC h3b). Block = (p-tile of 112, co2).
__global__ void wf1_prep_t(const float* __restrict__ wf1, ushort* __restrict__ wsg) {
    const int pt  = blockIdx.x;      // 0..6
    const int co2 = blockIdx.y;      // 0..127
    __shared__ ushort T[64][114];
#pragma unroll
    for (int k = 0; k < 7; ++k) {
        int i = threadIdx.x + k * 256;      // 0..1791 over [64 co][28 p-float4]
        int co = i / 28, pf = i % 28;
        const float4 v = *(const float4*)&wf1[(size_t)co2 * 50176 + co * 784 + pt * 112 + pf * 4];
        T[co][pf * 4 + 0] = sgn2bf(v.x);
        T[co][pf * 4 + 1] = sgn2bf(v.y);
        T[co][pf * 4 + 2] = sgn2bf(v.z);
        T[co][pf * 4 + 3] = sgn2bf(v.w);
    }
    __syncthreads();
#pragma unroll
    for (int k = 0; k < 7; ++k) {
        int j = threadIdx.x + k * 256;      // 0..1791 over [112 p][16 co-groups]
        int p = j >> 4, cg = j & 15;
        ushort pk[4] = {T[cg * 4 + 0][p], T[cg * 4 + 1][p], T[cg * 4 + 2][p], T[cg * 4 + 3][p]};
        *(short4v*)&wsg[(size_t)co2 * 50176 + (size_t)(pt * 112 + p) * 64 + cg * 4] =
            *(const short4v*)pk;
    }
}

// ---------------- conv1: MFMA im2col, quad A-rows, register maxpool -------------
// A-row r = quad (r>>2 = pooled px within tile), elem (r&3 = 2x2 position).
// Lane (llo,lhi): A-row llo -> pixel; D row lhi*4+j -> lane holds full quad in acc.
// grid (112, 1, 128), block 256 = 4 waves; wave wv -> pooled px wv*28 .. wv*28+27.
__global__ __launch_bounds__(256) void
conv1_mfma(const ushort* __restrict__ x4,    // [128,226,226,4] bf16
           const ushort* __restrict__ wfrag, // [2][64][8] bf16
           const float* __restrict__ bias,   // [16]
           ushort* __restrict__ h1p) {       // [128,114,114,16] bf16
    const int py = blockIdx.x;               // pooled row 0..111
    const int b  = blockIdx.z;
    const int wv = threadIdx.x >> 6, l = threadIdx.x & 63;
    const int lhi = l >> 4, llo = l & 15;
    const int q = llo >> 2, e = llo & 3;
    const int xpre0 = wv * 56 + 2 * q + (e & 1);   // + 8*i per m-tile
    const int ypre  = 2 * py + (e >> 1);

    short8 wf[2];
#pragma unroll
    for (int c = 0; c < 2; ++c)
        wf[c] = *(const short8*)&wfrag[(c * 64 + l) * 8];
    const float bv = bias[llo];

    const ushort* ptr[2]; bool vld[2];
#pragma unroll
    for (int c = 0; c < 2; ++c) {
        const int cc = c * 4 + lhi, ky = cc >> 1, half = cc & 1;
        vld[c] = (ky < 3);
        const int kyc = vld[c] ? ky : 0;
        ptr[c] = &x4[(((size_t)(b * 226 + ypre + kyc)) * 226 + xpre0 + 2 * half) * 4];
        // half=1 loads pixels x+2,x+3: kx=3 slot is garbage * zero-weight (safe)
    }

    f32x4 acc[7];
#pragma unroll
    for (int i = 0; i < 7; ++i) acc[i] = (f32x4){0.f, 0.f, 0.f, 0.f};

#pragma unroll
    for (int i = 0; i < 7; ++i)
#pragma unroll
        for (int c = 0; c < 2; ++c) {
            short8 a = {};
            if (vld[c]) a = (short8)(*(const short8u*)(ptr[c] + i * 32));
            acc[i] = __builtin_amdgcn_mfma_f32_16x16x32_bf16(a, wf[c], acc[i], 0, 0, 0);
        }

    const size_t obase = ((size_t)(b * 114 + 1 + py) * 114 + 1) * 16 + llo;
#pragma unroll
    for (int i = 0; i < 7; ++i) {
        float v = fmaxf(fmaxf(acc[i][0], acc[i][1]), fmaxf(acc[i][2], acc[i][3]));
        v = fmaxf(v + bv, 0.f);
        h1p[obase + (size_t)(wv * 28 + i * 4 + lhi) * 16] = f2bf(v);
    }
}

// ---------------- conv2: MFMA im2col, quad A-rows, register maxpool -------------
// grid (56, 1, 128), block 256 = 4 waves: wave -> (mh = wv>>1, n = wv&1)
__global__ __launch_bounds__(256) void
conv2_mfma(const ushort* __restrict__ h1p,   // [128,114,114,16] bf16
           const ushort* __restrict__ wfrag, // [5][2][64][8] bf16
           const float* __restrict__ bias,   // [32]
           ushort* __restrict__ h2p) {       // [128,58,58,32] bf16
    const int py = blockIdx.x;               // pooled row 0..55
    const int b  = blockIdx.z;
    const int wv = threadIdx.x >> 6, l = threadIdx.x & 63;
    const int mh = wv >> 1, n = wv & 1;
    const int lhi = l >> 4, llo = l & 15;
    const int q = llo >> 2, e = llo & 3;
    const int xpre0 = mh * 56 + 2 * q + (e & 1);
    const int ypre  = 2 * py + (e >> 1);

    short8 wf[5];
#pragma unroll
    for (int c = 0; c < 5; ++c)
        wf[c] = *(const short8*)&wfrag[(((c * 2 + n) * 64) + l) * 8];
    const float bv = bias[n * 16 + llo];

    const ushort* ptr[5]; bool vld[5];
#pragma unroll
    for (int c = 0; c < 5; ++c) {
        const int cc = c * 4 + lhi;          // 0..19, valid < 18
        vld[c] = (cc < 18);
        const int dy = vld[c] ? (cc / 6) : 0;
        const int koff = (cc % 6) * 8;
        ptr[c] = &h1p[(((size_t)(b * 114 + ypre + dy)) * 114 + xpre0) * 16 + koff];
    }

    f32x4 acc[7];
#pragma unroll
    for (int m = 0; m < 7; ++m) acc[m] = (f32x4){0.f, 0.f, 0.f, 0.f};

#pragma unroll
    for (int m = 0; m < 7; ++m)
#pragma unroll
        for (int c = 0; c < 5; ++c) {
            short8 a = {};
            if (vld[c]) a = *(const short8*)(ptr[c] + m * 128);
            acc[m] = __builtin_amdgcn_mfma_f32_16x16x32_bf16(a, wf[c], acc[m], 0, 0, 0);
        }

    const size_t obase = ((size_t)(b * 58 + 1 + py) * 58 + 1) * 32 + n * 16 + llo;
#pragma unroll
    for (int m = 0; m < 7; ++m) {
        float v = fmaxf(fmaxf(acc[m][0], acc[m][1]), fmaxf(acc[m][2], acc[m][3]));
        v = fmaxf(v + bv, 0.f);
        h2p[obase + (size_t)(mh * 28 + m * 4 + lhi) * 32] = f2bf(v);
    }
}

// ---------------- conv3: MFMA im2col, quad A-rows, NHWC bf16 out ----------------
// grid (28, 1, 128), block 256 = 4 waves: wave = co-tile n; m-tiles 0..6 each.
// h3b[b][ (py*28+px)*64 + co ] -- K-permuted flatten matching wf1_prep_t.
__global__ __launch_bounds__(256) void
conv3_mfma(const ushort* __restrict__ h2p,   // [128,58,58,32] bf16
           const ushort* __restrict__ wfrag, // [9][4][64][8] bf16
           const float* __restrict__ bias,   // [64]
           ushort* __restrict__ h3b) {       // [128][50176] bf16 (p*64+co)
    const int py = blockIdx.x;               // pooled row 0..27
    const int b  = blockIdx.z;
    const int n = threadIdx.x >> 6, l = threadIdx.x & 63;
    const int lhi = l >> 4, llo = l & 15;
    const int q = llo >> 2, e = llo & 3;
    const int xpre0 = 2 * q + (e & 1);
    const int ypre  = 2 * py + (e >> 1);

    short8 wf[9];
#pragma unroll
    for (int c = 0; c < 9; ++c)
        wf[c] = *(const short8*)&wfrag[(((c * 4 + n) * 64) + l) * 8];
    const float bv = bias[n * 16 + llo];

    const ushort* ptr[9];
#pragma unroll
    for (int c = 0; c < 9; ++c) {
        const int cc = c * 4 + lhi;          // 0..35, all valid
        const int dy = cc / 12, koff = (cc % 12) * 8;
        ptr[c] = &h2p[(((size_t)(b * 58 + ypre + dy)) * 58 + xpre0) * 32 + koff];
    }

    f32x4 acc[7];
#pragma unroll
    for (int m = 0; m < 7; ++m) acc[m] = (f32x4){0.f, 0.f, 0.f, 0.f};

#pragma unroll
    for (int m = 0; m < 7; ++m)
#pragma unroll
        for (int c = 0; c < 9; ++c) {
            short8 a = *(const short8*)(ptr[c] + m * 256);
            acc[m] = __builtin_amdgcn_mfma_f32_16x16x32_bf16(a, wf[c], acc[m], 0, 0, 0);
        }

    const size_t obase = (size_t)b * 50176 + (size_t)(py * 28) * 64 + n * 16 + llo;
#pragma unroll
    for (int m = 0; m < 7; ++m) {
        float v = fmaxf(fmaxf(acc[m][0], acc[m][1]), fmaxf(acc[m][2], acc[m][3]));
        v = fmaxf(v + bv, 0.f);
        h3b[obase + (size_t)(m * 4 + lhi) * 64] = f2bf(v);
    }
}

// ---------------- FC1 stage A: bf16 MFMA split-K GEMM ---------------------------
__global__ __launch_bounds__(256) void
fc1_mfmaA(const ushort* __restrict__ actb,  // [128][50176] bf16 (K-permuted)
          const ushort* __restrict__ wsg,   // [128][50176] bf16 (same K-perm)
          float* __restrict__ partials) {   // [49][128][128]
    const int K = 50176;
    const int bt = blockIdx.x * 32, ct = blockIdx.y * 32, ks = blockIdx.z;
    const int wv = threadIdx.x >> 6, l = threadIdx.x & 63;
    const int lhi = l >> 4, llo = l & 15;

    __shared__ float lds[4][32][33];

    f32x4 acc[2][2];
#pragma unroll
    for (int i = 0; i < 2; ++i)
#pragma unroll
        for (int j = 0; j < 2; ++j) acc[i][j] = (f32x4){0.f, 0.f, 0.f, 0.f};

    const int kw = ks * 1024 + wv * 256 + lhi * 8;
    const ushort* a0p = actb + (size_t)(bt + llo)      * K + kw;
    const ushort* a1p = actb + (size_t)(bt + llo + 16) * K + kw;
    const ushort* b0p = wsg  + (size_t)(ct + llo)      * K + kw;
    const ushort* b1p = wsg  + (size_t)(ct + llo + 16) * K + kw;

#pragma unroll
    for (int s = 0; s < 8; ++s) {
        const int off = s * 32;
        const short8 a0 = *(const short8*)(a0p + off);
        const short8 a1 = *(const short8*)(a1p + off);
        const short8 b0 = *(const short8*)(b0p + off);
        const short8 b1 = *(const short8*)(b1p + off);
        acc[0][0] = __builtin_amdgcn_mfma_f32_16x16x32_bf16(a0, b0, acc[0][0], 0, 0, 0);
        acc[0][1] = __builtin_amdgcn_mfma_f32_16x16x32_bf16(a0, b1, acc[0][1], 0, 0, 0);
        acc[1][0] = __builtin_amdgcn_mfma_f32_16x16x32_bf16(a1, b0, acc[1][0], 0, 0, 0);
        acc[1][1] = __builtin_amdgcn_mfma_f32_16x16x32_bf16(a1, b1, acc[1][1], 0, 0, 0);
    }

#pragma unroll
    for (int i = 0; i < 2; ++i)
#pragma unroll
        for (int jj = 0; jj < 2; ++jj)
#pragma unroll
            for (int j = 0; j < 4; ++j)
                lds[wv][i * 16 + lhi * 4 + j][jj * 16 + llo] = acc[i][jj][j];
    __syncthreads();

    float* pb = partials + (size_t)ks * 16384;
#pragma unroll
    for (int u = 0; u < 4; ++u) {
        int idx = threadIdx.x + u * 256;     // 0..1023
        int m = idx >> 5, n = idx & 31;
        float v = lds[0][m][n] + lds[1][m][n] + lds[2][m][n] + lds[3][m][n];
        pb[(bt + m) * 128 + ct + n] = v;
    }
}

// ---------------- FC1 stage B: reduce 49 partials + bias + relu -----------------
__global__ void fc1_stageB(const float* __restrict__ partials,
                           const float* __restrict__ bf,
                           float* __restrict__ f1) {
    const int o = blockIdx.x * 256 + threadIdx.x;  // 0..16383
    float acc = 0.f;
    for (int ks = 0; ks < 49; ++ks) acc += partials[(size_t)ks * 16384 + o];
    f1[o] = fmaxf(acc + bf[o & 127], 0.f);
}

// ---------------- FC2 ------------------------------------------------------------
__global__ void fc2_kernel(const float* __restrict__ act,
                           const float* __restrict__ wf,
                           const float* __restrict__ bf,
                           float* __restrict__ out) {
    const int o = blockIdx.x * 256 + threadIdx.x;
    if (o >= 128 * 1000) return;
    const int b = o / 1000, co = o % 1000;
    const float* a  = act + b * 128;
    const float* wr = wf + co * 128;
    float acc = 0.f;
#pragma unroll 8
    for (int k = 0; k < 128; ++k)
        acc = fmaf(a[k], sgn(wr[k]), acc);
    out[o] = acc + bf[co];
}

extern "C" void kernel_launch(void* const* d_in, const int* in_sizes, int n_in,
                              void* d_out, int out_size, void* d_ws, size_t ws_size,
                              hipStream_t stream) {
    const float* x   = (const float*)d_in[0];
    const float* w1  = (const float*)d_in[1];
    const float* b1  = (const float*)d_in[2];
    const float* w2  = (const float*)d_in[3];
    const float* b2  = (const float*)d_in[4];
    const float* w3  = (const float*)d_in[5];
    const float* b3  = (const float*)d_in[6];
    const float* wf1 = (const float*)d_in[7];
    const float* bf1 = (const float*)d_in[8];
    const float* wf2 = (const float*)d_in[9];
    const float* bf2 = (const float*)d_in[10];

    // ws layout (peak 133.1 MB):
    //   h1p bf16 [128,114,114,16] @ 0            (53,231,616)
    //   x4  bf16 [128,226,226,4]  @ 53,231,616   (52,276,224)  dead after conv1
    //     overlaid on dead x4:
    //     h3b  bf16 [128][50176]  @ 53,231,616   (12,845,056)  NHWC-permuted K
    //     wsg1 bf16 [128][50176]  @ 66,076,672   (12,845,056)  same K-perm
    //     pa   fp32 [49][16384]   @ 78,921,728   ( 3,211,264)
    //     f1   fp32 [128,128]     @ 82,132,992   (    65,536)
    //   h2p bf16 [128,58,58,32]   @ 105,507,840  (27,557,888)
    //   wf1frag @ 133,065,728 (2,048); wf2frag @ 133,067,776 (10,240);
    //   wf3frag @ 133,078,016 (36,864)
    char* ws = (char*)d_ws;
    ushort* h1p  = (ushort*)ws;
    ushort* x4   = (ushort*)(ws + 53231616u);
    ushort* h3b  = (ushort*)(ws + 53231616u);
    ushort* wsg1 = (ushort*)(ws + 66076672u);
    float*  pa   = (float*) (ws + 78921728u);
    float*  f1   = (float*) (ws + 82132992u);
    ushort* h2p  = (ushort*)(ws + 105507840u);
    ushort* wf1frag = (ushort*)(ws + 133065728u);
    ushort* wf2frag = (ushort*)(ws + 133067776u);
    ushort* wf3frag = (ushort*)(ws + 133078016u);

    pad_zero<<<7265, 256, 0, stream>>>(h1p, h2p);
    wfrag_prep<<<96, 256, 0, stream>>>(w2, w3, w1, wf2frag, wf3frag, wf1frag);
    x4_prep<<<25538, 256, 0, stream>>>(x, x4);
    conv1_mfma<<<dim3(112, 1, 128), 256, 0, stream>>>(x4, wf1frag, b1, h1p);
    // x4 now dead; regions overlaying it may be written from here on
    wf1_prep_t<<<dim3(7, 128), 256, 0, stream>>>(wf1, wsg1);
    conv2_mfma<<<dim3(56, 1, 128), 256, 0, stream>>>(h1p, wf2frag, b2, h2p);
    conv3_mfma<<<dim3(28, 1, 128), 256, 0, stream>>>(h2p, wf3frag, b3, h3b);
    fc1_mfmaA<<<dim3(4, 4, 49), 256, 0, stream>>>(h3b, wsg1, pa);
    fc1_stageB<<<64, 256, 0, stream>>>(pa, bf1, f1);
    fc2_kernel<<<500, 256, 0, stream>>>(f1, wf2, bf2, (float*)d_out);
}

// Round 9
// 218.668 us; speedup vs baseline: 22.9844x; 1.0129x over previous
//
#include <hip/hip_runtime.h>

typedef __attribute__((ext_vector_type(8))) short short8;
typedef __attribute__((ext_vector_type(8), aligned(8))) short short8u;  // 8B-aligned 16B load
typedef __attribute__((ext_vector_type(4))) short short4v;
typedef __attribute__((ext_vector_type(4))) float f32x4;
typedef unsigned short ushort;
typedef unsigned int uint;

static __device__ __forceinline__ float sgn(float v) {
    return (v > 0.f) ? 1.f : ((v < 0.f) ? -1.f : 0.f);
}
static __device__ __forceinline__ ushort f2bf(float f) {
    uint u = __builtin_bit_cast(uint, f);
    u += 0x7fffu + ((u >> 16) & 1u);   // RNE
    return (ushort)(u >> 16);
}
static __device__ __forceinline__ ushort sgn2bf(float v) {
    return (v > 0.f) ? (ushort)0x3F80 : ((v < 0.f) ? (ushort)0xBF80 : (ushort)0);
}

// ---------------- pad-zero: zero the halo borders of h1p and h2p ----------------
__global__ void pad_zero(ushort* __restrict__ h1p, ushort* __restrict__ h2p) {
    int t = blockIdx.x * 256 + threadIdx.x;
    if (t < 925696) {                       // h1p: 128 b x 452 cells x 16 ch
        int b = t / 7232, r = t % 7232;
        int cell = r >> 4, ch = r & 15;
        int y, x;
        if (cell < 114)      { y = 0;   x = cell; }
        else if (cell < 228) { y = 113; x = cell - 114; }
        else { int s = cell - 228; y = 1 + (s >> 1); x = (s & 1) ? 113 : 0; }
        h1p[((b * 114 + y) * 114 + x) * 16 + ch] = 0;
    } else {
        t -= 925696;
        if (t >= 933888) return;            // h2p: 128 b x 228 cells x 32 ch
        int b = t / 7296, r = t % 7296;
        int cell = r >> 5, ch = r & 31;
        int y, x;
        if (cell < 58)       { y = 0;  x = cell; }
        else if (cell < 116) { y = 57; x = cell - 58; }
        else { int s = cell - 116; y = 1 + (s >> 1); x = (s & 1) ? 57 : 0; }
        h2p[((b * 58 + y) * 58 + x) * 32 + ch] = 0;
    }
}

// ---------------- x4_prep: x NCHW fp32 -> padded NHWC-4ch bf16 ------------------
__global__ void x4_prep(const float* __restrict__ x,   // [128,3,224,224]
                        ushort* __restrict__ x4) {
    int t = blockIdx.x * 256 + threadIdx.x;
    if (t >= 128 * 51076) return;
    int b = t / 51076, pix = t % 51076;
    int Y = pix / 226, X = pix % 226;
    ushort pk[4] = {0, 0, 0, 0};
    if (Y >= 1 && Y <= 224 && X >= 1 && X <= 224) {
        const float* xb = x + ((size_t)b * 3) * 50176 + (Y - 1) * 224 + (X - 1);
        pk[0] = f2bf(xb[0]);
        pk[1] = f2bf(xb[50176]);
        pk[2] = f2bf(xb[100352]);
    }
    *(short4v*)&x4[(size_t)t * 4] = *(const short4v*)pk;
}

// ---------------- weight-fragment prep (sgn -> bf16, MFMA fragment order) -------
__global__ void wfrag_prep(const float* __restrict__ w2, const float* __restrict__ w3,
                           const float* __restrict__ w1,
                           ushort* __restrict__ f2, ushort* __restrict__ f3,
                           ushort* __restrict__ f1) {
    int t = blockIdx.x * 256 + threadIdx.x;
    if (t < 5120) {
        int j = t & 7, l = (t >> 3) & 63, nc = t >> 9;  // nc = c*2 + n
        int n = nc & 1, c = nc >> 1;
        int k = c * 32 + ((l >> 4) << 3) + j;
        ushort v = 0;
        if (k < 144) {
            int ky = k / 48, rem = k % 48, kx = rem >> 4, ci = rem & 15;
            int co = n * 16 + (l & 15);
            v = sgn2bf(w2[((co * 16 + ci) * 3 + ky) * 3 + kx]);
        }
        f2[t] = v;
    } else if (t < 23552) {
        int t2 = t - 5120;
        int j = t2 & 7, l = (t2 >> 3) & 63, nc = t2 >> 9;  // nc = c*4 + n
        int n = nc & 3, c = nc >> 2;
        int k = c * 32 + ((l >> 4) << 3) + j;               // < 288
        int ky = k / 96, rem = k % 96, kx = rem >> 5, ci = rem & 31;
        int co = n * 16 + (l & 15);
        f3[t2] = sgn2bf(w3[((co * 32 + ci) * 3 + ky) * 3 + kx]);
    } else {
        int t1 = t - 23552;
        if (t1 >= 1024) return;
        int j = t1 & 7, l = (t1 >> 3) & 63, c = t1 >> 9;    // c = 0,1
        int k = c * 32 + ((l >> 4) << 3) + j;               // 0..63
        int ky = k >> 4, kx = (k >> 2) & 3, ci = k & 3;
        ushort v = 0;
        if (ky < 3 && kx < 3 && ci < 3) {
            int co = l & 15;
            v = sgn2bf(w1[((co * 3 + ci) * 3 + ky) * 3 + kx]);
        }
        f1[t1] = v;
    }
}

// ---------------- wf1_prep_t: wf1 fp32 [128][50176] -> sign bf16, K-permuted ----
__global__ void wf1_prep_t(const float* __restrict__ wf1, ushort* __restrict__ wsg) {
    const int pt  = blockIdx.x;      // 0..6
    const int co2 = blockIdx.y;      // 0..127
    __shared__ ushort T[64][114];
#pragma unroll
    for (int k = 0; k < 7; ++k) {
        int i = threadIdx.x + k * 256;      // 0..1791 over [64 co][28 p-float4]
        int co = i / 28, pf = i % 28;
        const float4 v = *(const float4*)&wf1[(size_t)co2 * 50176 + co * 784 + pt * 112 + pf * 4];
        T[co][pf * 4 + 0] = sgn2bf(v.x);
        T[co][pf * 4 + 1] = sgn2bf(v.y);
        T[co][pf * 4 + 2] = sgn2bf(v.z);
        T[co][pf * 4 + 3] = sgn2bf(v.w);
    }
    __syncthreads();
#pragma unroll
    for (int k = 0; k < 7; ++k) {
        int j = threadIdx.x + k * 256;      // 0..1791 over [112 p][16 co-groups]
        int p = j >> 4, cg = j & 15;
        ushort pk[4] = {T[cg * 4 + 0][p], T[cg * 4 + 1][p], T[cg * 4 + 2][p], T[cg * 4 + 3][p]};
        *(short4v*)&wsg[(size_t)co2 * 50176 + (size_t)(pt * 112 + p) * 64 + cg * 4] =
            *(const short4v*)pk;
    }
}

// ---------------- conv1: MFMA im2col, quad A-rows, register maxpool -------------
// Loads batched into named registers (memory ILP); math identical to r8.
__global__ __launch_bounds__(256) void
conv1_mfma(const ushort* __restrict__ x4,    // [128,226,226,4] bf16
           const ushort* __restrict__ wfrag, // [2][64][8] bf16
           const float* __restrict__ bias,   // [16]
           ushort* __restrict__ h1p) {       // [128,114,114,16] bf16
    const int py = blockIdx.x;               // pooled row 0..111
    const int b  = blockIdx.z;
    const int wv = threadIdx.x >> 6, l = threadIdx.x & 63;
    const int lhi = l >> 4, llo = l & 15;
    const int q = llo >> 2, e = llo & 3;
    const int xpre0 = wv * 56 + 2 * q + (e & 1);
    const int ypre  = 2 * py + (e >> 1);

    short8 wf[2];
#pragma unroll
    for (int c = 0; c < 2; ++c)
        wf[c] = *(const short8*)&wfrag[(c * 64 + l) * 8];
    const float bv = bias[llo];

    const ushort* ptr[2]; bool vld[2];
#pragma unroll
    for (int c = 0; c < 2; ++c) {
        const int cc = c * 4 + lhi, ky = cc >> 1, half = cc & 1;
        vld[c] = (ky < 3);
        const int kyc = vld[c] ? ky : 0;
        ptr[c] = &x4[(((size_t)(b * 226 + ypre + kyc)) * 226 + xpre0 + 2 * half) * 4];
    }

    // batch ALL 14 A-fragment loads first -> 14 loads in flight
    short8 a[7][2];
#pragma unroll
    for (int i = 0; i < 7; ++i)
#pragma unroll
        for (int c = 0; c < 2; ++c) {
            short8 t = {};
            if (vld[c]) t = (short8)(*(const short8u*)(ptr[c] + i * 32));
            a[i][c] = t;
        }

    f32x4 acc[7];
#pragma unroll
    for (int i = 0; i < 7; ++i) acc[i] = (f32x4){0.f, 0.f, 0.f, 0.f};
#pragma unroll
    for (int i = 0; i < 7; ++i)
#pragma unroll
        for (int c = 0; c < 2; ++c)
            acc[i] = __builtin_amdgcn_mfma_f32_16x16x32_bf16(a[i][c], wf[c], acc[i], 0, 0, 0);

    const size_t obase = ((size_t)(b * 114 + 1 + py) * 114 + 1) * 16 + llo;
#pragma unroll
    for (int i = 0; i < 7; ++i) {
        float v = fmaxf(fmaxf(acc[i][0], acc[i][1]), fmaxf(acc[i][2], acc[i][3]));
        v = fmaxf(v + bv, 0.f);
        h1p[obase + (size_t)(wv * 28 + i * 4 + lhi) * 16] = f2bf(v);
    }
}

// ---------------- conv2: MFMA im2col, quad A-rows, register maxpool -------------
__global__ __launch_bounds__(256) void
conv2_mfma(const ushort* __restrict__ h1p,   // [128,114,114,16] bf16
           const ushort* __restrict__ wfrag, // [5][2][64][8] bf16
           const float* __restrict__ bias,   // [32]
           ushort* __restrict__ h2p) {       // [128,58,58,32] bf16
    const int py = blockIdx.x;               // pooled row 0..55
    const int b  = blockIdx.z;
    const int wv = threadIdx.x >> 6, l = threadIdx.x & 63;
    const int mh = wv >> 1, n = wv & 1;
    const int lhi = l >> 4, llo = l & 15;
    const int q = llo >> 2, e = llo & 3;
    const int xpre0 = mh * 56 + 2 * q + (e & 1);
    const int ypre  = 2 * py + (e >> 1);

    short8 wf[5];
#pragma unroll
    for (int c = 0; c < 5; ++c)
        wf[c] = *(const short8*)&wfrag[(((c * 2 + n) * 64) + l) * 8];
    const float bv = bias[n * 16 + llo];

    const ushort* ptr[5]; bool vld[5];
#pragma unroll
    for (int c = 0; c < 5; ++c) {
        const int cc = c * 4 + lhi;          // 0..19, valid < 18
        vld[c] = (cc < 18);
        const int dy = vld[c] ? (cc / 6) : 0;
        const int koff = (cc % 6) * 8;
        ptr[c] = &h1p[(((size_t)(b * 114 + ypre + dy)) * 114 + xpre0) * 16 + koff];
    }

    f32x4 acc[7];
#pragma unroll
    for (int m = 0; m < 7; ++m) acc[m] = (f32x4){0.f, 0.f, 0.f, 0.f};

    // per k-step: batch 7 independent loads, then 7 independent MFMAs
#pragma unroll
    for (int c = 0; c < 5; ++c) {
        short8 a[7];
#pragma unroll
        for (int m = 0; m < 7; ++m) {
            short8 t = {};
            if (vld[c]) t = *(const short8*)(ptr[c] + m * 128);
            a[m] = t;
        }
#pragma unroll
        for (int m = 0; m < 7; ++m)
            acc[m] = __builtin_amdgcn_mfma_f32_16x16x32_bf16(a[m], wf[c], acc[m], 0, 0, 0);
    }

    const size_t obase = ((size_t)(b * 58 + 1 + py) * 58 + 1) * 32 + n * 16 + llo;
#pragma unroll
    for (int m = 0; m < 7; ++m) {
        float v = fmaxf(fmaxf(acc[m][0], acc[m][1]), fmaxf(acc[m][2], acc[m][3]));
        v = fmaxf(v + bv, 0.f);
        h2p[obase + (size_t)(mh * 28 + m * 4 + lhi) * 32] = f2bf(v);
    }
}

// ---------------- conv3: MFMA im2col, quad A-rows, NHWC bf16 out ----------------
__global__ __launch_bounds__(256) void
conv3_mfma(const ushort* __restrict__ h2p,   // [128,58,58,32] bf16
           const ushort* __restrict__ wfrag, // [9][4][64][8] bf16
           const float* __restrict__ bias,   // [64]
           ushort* __restrict__ h3b) {       // [128][50176] bf16 (p*64+co)
    const int py = blockIdx.x;               // pooled row 0..27
    const int b  = blockIdx.z;
    const int n = threadIdx.x >> 6, l = threadIdx.x & 63;
    const int lhi = l >> 4, llo = l & 15;
    const int q = llo >> 2, e = llo & 3;
    const int xpre0 = 2 * q + (e & 1);
    const int ypre  = 2 * py + (e >> 1);

    short8 wf[9];
#pragma unroll
    for (int c = 0; c < 9; ++c)
        wf[c] = *(const short8*)&wfrag[(((c * 4 + n) * 64) + l) * 8];
    const float bv = bias[n * 16 + llo];

    const ushort* ptr[9];
#pragma unroll
    for (int c = 0; c < 9; ++c) {
        const int cc = c * 4 + lhi;          // 0..35, all valid
        const int dy = cc / 12, koff = (cc % 12) * 8;
        ptr[c] = &h2p[(((size_t)(b * 58 + ypre + dy)) * 58 + xpre0) * 32 + koff];
    }

    f32x4 acc[7];
#pragma unroll
    for (int m = 0; m < 7; ++m) acc[m] = (f32x4){0.f, 0.f, 0.f, 0.f};

#pragma unroll
    for (int c = 0; c < 9; ++c) {
        short8 a[7];
#pragma unroll
        for (int m = 0; m < 7; ++m)
            a[m] = *(const short8*)(ptr[c] + m * 256);
#pragma unroll
        for (int m = 0; m < 7; ++m)
            acc[m] = __builtin_amdgcn_mfma_f32_16x16x32_bf16(a[m], wf[c], acc[m], 0, 0, 0);
    }

    const size_t obase = (size_t)b * 50176 + (size_t)(py * 28) * 64 + n * 16 + llo;
#pragma unroll
    for (int m = 0; m < 7; ++m) {
        float v = fmaxf(fmaxf(acc[m][0], acc[m][1]), fmaxf(acc[m][2], acc[m][3]));
        v = fmaxf(v + bv, 0.f);
        h3b[obase + (size_t)(m * 4 + lhi) * 64] = f2bf(v);
    }
}

// ---------------- FC1 stage A: bf16 MFMA split-K GEMM ---------------------------
__global__ __launch_bounds__(256) void
fc1_mfmaA(const ushort* __restrict__ actb,  // [128][50176] bf16 (K-permuted)
          const ushort* __restrict__ wsg,   // [128][50176] bf16 (same K-perm)
          float* __restrict__ partials) {   // [49][128][128]
    const int K = 50176;
    const int bt = blockIdx.x * 32, ct = blockIdx.y * 32, ks = blockIdx.z;
    const int wv = threadIdx.x >> 6, l = threadIdx.x & 63;
    const int lhi = l >> 4, llo = l & 15;

    __shared__ float lds[4][32][33];

    f32x4 acc[2][2];
#pragma unroll
    for (int i = 0; i < 2; ++i)
#pragma unroll
        for (int j = 0; j < 2; ++j) acc[i][j] = (f32x4){0.f, 0.f, 0.f, 0.f};

    const int kw = ks * 1024 + wv * 256 + lhi * 8;
    const ushort* a0p = actb + (size_t)(bt + llo)      * K + kw;
    const ushort* a1p = actb + (size_t)(bt + llo + 16) * K + kw;
    const ushort* b0p = wsg  + (size_t)(ct + llo)      * K + kw;
    const ushort* b1p = wsg  + (size_t)(ct + llo + 16) * K + kw;

#pragma unroll
    for (int s = 0; s < 8; ++s) {
        const int off = s * 32;
        const short8 a0 = *(const short8*)(a0p + off);
        const short8 a1 = *(const short8*)(a1p + off);
        const short8 b0 = *(const short8*)(b0p + off);
        const short8 b1 = *(const short8*)(b1p + off);
        acc[0][0] = __builtin_amdgcn_mfma_f32_16x16x32_bf16(a0, b0, acc[0][0], 0, 0, 0);
        acc[0][1] = __builtin_amdgcn_mfma_f32_16x16x32_bf16(a0, b1, acc[0][1], 0, 0, 0);
        acc[1][0] = __builtin_amdgcn_mfma_f32_16x16x32_bf16(a1, b0, acc[1][0], 0, 0, 0);
        acc[1][1] = __builtin_amdgcn_mfma_f32_16x16x32_bf16(a1, b1, acc[1][1], 0, 0, 0);
    }

#pragma unroll
    for (int i = 0; i < 2; ++i)
#pragma unroll
        for (int jj = 0; jj < 2; ++jj)
#pragma unroll
            for (int j = 0; j < 4; ++j)
                lds[wv][i * 16 + lhi * 4 + j][jj * 16 + llo] = acc[i][jj][j];
    __syncthreads();

    float* pb = partials + (size_t)ks * 16384;
#pragma unroll
    for (int u = 0; u < 4; ++u) {
        int idx = threadIdx.x + u * 256;     // 0..1023
        int m = idx >> 5, n = idx & 31;
        float v = lds[0][m][n] + lds[1][m][n] + lds[2][m][n] + lds[3][m][n];
        pb[(bt + m) * 128 + ct + n] = v;
    }
}

// ---------------- FC1 stage B: reduce 49 partials + bias + relu -----------------
__global__ void fc1_stageB(const float* __restrict__ partials,
                           const float* __restrict__ bf,
                           float* __restrict__ f1) {
    const int o = blockIdx.x * 256 + threadIdx.x;  // 0..16383
    float acc = 0.f;
    for (int ks = 0; ks < 49; ++ks) acc += partials[(size_t)ks * 16384 + o];
    f1[o] = fmaxf(acc + bf[o & 127], 0.f);
}

// ---------------- FC2 ------------------------------------------------------------
__global__ void fc2_kernel(const float* __restrict__ act,
                           const float* __restrict__ wf,
                           const float* __restrict__ bf,
                           float* __restrict__ out) {
    const int o = blockIdx.x * 256 + threadIdx.x;
    if (o >= 128 * 1000) return;
    const int b = o / 1000, co = o % 1000;
    const float* a  = act + b * 128;
    const float* wr = wf + co * 128;
    float acc = 0.f;
#pragma unroll 8
    for (int k = 0; k < 128; ++k)
        acc = fmaf(a[k], sgn(wr[k]), acc);
    out[o] = acc + bf[co];
}

extern "C" void kernel_launch(void* const* d_in, const int* in_sizes, int n_in,
                              void* d_out, int out_size, void* d_ws, size_t ws_size,
                              hipStream_t stream) {
    const float* x   = (const float*)d_in[0];
    const float* w1  = (const float*)d_in[1];
    const float* b1  = (const float*)d_in[2];
    const float* w2  = (const float*)d_in[3];
    const float* b2  = (const float*)d_in[4];
    const float* w3  = (const float*)d_in[5];
    const float* b3  = (const float*)d_in[6];
    const float* wf1 = (const float*)d_in[7];
    const float* bf1 = (const float*)d_in[8];
    const float* wf2 = (const float*)d_in[9];
    const float* bf2 = (const float*)d_in[10];

    // ws layout (peak 133.1 MB):
    //   h1p bf16 [128,114,114,16] @ 0            (53,231,616)
    //   x4  bf16 [128,226,226,4]  @ 53,231,616   (52,276,224)  dead after conv1
    //     overlaid on dead x4:
    //     h3b  bf16 [128][50176]  @ 53,231,616   (12,845,056)  NHWC-permuted K
    //     wsg1 bf16 [128][50176]  @ 66,076,672   (12,845,056)  same K-perm
    //     pa   fp32 [49][16384]   @ 78,921,728   ( 3,211,264)
    //     f1   fp32 [128,128]     @ 82,132,992   (    65,536)
    //   h2p bf16 [128,58,58,32]   @ 105,507,840  (27,557,888)
    //   wf1frag @ 133,065,728 (2,048); wf2frag @ 133,067,776 (10,240);
    //   wf3frag @ 133,078,016 (36,864)
    char* ws = (char*)d_ws;
    ushort* h1p  = (ushort*)ws;
    ushort* x4   = (ushort*)(ws + 53231616u);
    ushort* h3b  = (ushort*)(ws + 53231616u);
    ushort* wsg1 = (ushort*)(ws + 66076672u);
    float*  pa   = (float*) (ws + 78921728u);
    float*  f1   = (float*) (ws + 82132992u);
    ushort* h2p  = (ushort*)(ws + 105507840u);
    ushort* wf1frag = (ushort*)(ws + 133065728u);
    ushort* wf2frag = (ushort*)(ws + 133067776u);
    ushort* wf3frag = (ushort*)(ws + 133078016u);

    pad_zero<<<7265, 256, 0, stream>>>(h1p, h2p);
    wfrag_prep<<<96, 256, 0, stream>>>(w2, w3, w1, wf2frag, wf3frag, wf1frag);
    x4_prep<<<25538, 256, 0, stream>>>(x, x4);
    conv1_mfma<<<dim3(112, 1, 128), 256, 0, stream>>>(x4, wf1frag, b1, h1p);
    // x4 now dead; regions overlaying it may be written from here on
    wf1_prep_t<<<dim3(7, 128), 256, 0, stream>>>(wf1, wsg1);
    conv2_mfma<<<dim3(56, 1, 128), 256, 0, stream>>>(h1p, wf2frag, b2, h2p);
    conv3_mfma<<<dim3(28, 1, 128), 256, 0, stream>>>(h2p, wf3frag, b3, h3b);
    fc1_mfmaA<<<dim3(4, 4, 49), 256, 0, stream>>>(h3b, wsg1, pa);
    fc1_stageB<<<64, 256, 0, stream>>>(pa, bf1, f1);
    fc2_kernel<<<500, 256, 0, stream>>>(f1, wf2, bf2, (float*)d_out);
}

// Round 10
// 175.523 us; speedup vs baseline: 28.6342x; 1.2458x over previous
//
#include <hip/hip_runtime.h>

typedef __attribute__((ext_vector_type(8))) short short8;
typedef __attribute__((ext_vector_type(8), aligned(8))) short short8u;  // 8B-aligned 16B load
typedef __attribute__((ext_vector_type(4))) short short4v;
typedef __attribute__((ext_vector_type(4))) float f32x4;
typedef unsigned short ushort;
typedef unsigned int uint;

static __device__ __forceinline__ float sgn(float v) {
    return (v > 0.f) ? 1.f : ((v < 0.f) ? -1.f : 0.f);
}
static __device__ __forceinline__ ushort f2bf(float f) {
    uint u = __builtin_bit_cast(uint, f);
    u += 0x7fffu + ((u >> 16) & 1u);   // RNE
    return (ushort)(u >> 16);
}
static __device__ __forceinline__ ushort sgn2bf(float v) {
    return (v > 0.f) ? (ushort)0x3F80 : ((v < 0.f) ? (ushort)0xBF80 : (ushort)0);
}

// ---------------- pad-zero: zero the halo borders of h1p and h2p ----------------
__global__ void pad_zero(ushort* __restrict__ h1p, ushort* __restrict__ h2p) {
    int t = blockIdx.x * 256 + threadIdx.x;
    if (t < 925696) {                       // h1p: 128 b x 452 cells x 16 ch
        int b = t / 7232, r = t % 7232;
        int cell = r >> 4, ch = r & 15;
        int y, x;
        if (cell < 114)      { y = 0;   x = cell; }
        else if (cell < 228) { y = 113; x = cell - 114; }
        else { int s = cell - 228; y = 1 + (s >> 1); x = (s & 1) ? 113 : 0; }
        h1p[((b * 114 + y) * 114 + x) * 16 + ch] = 0;
    } else {
        t -= 925696;
        if (t >= 933888) return;            // h2p: 128 b x 228 cells x 32 ch
        int b = t / 7296, r = t % 7296;
        int cell = r >> 5, ch = r & 31;
        int y, x;
        if (cell < 58)       { y = 0;  x = cell; }
        else if (cell < 116) { y = 57; x = cell - 58; }
        else { int s = cell - 116; y = 1 + (s >> 1); x = (s & 1) ? 57 : 0; }
        h2p[((b * 58 + y) * 58 + x) * 32 + ch] = 0;
    }
}

// ---------------- x4_prep: x NCHW fp32 -> padded NHWC-4ch bf16 ------------------
__global__ void x4_prep(const float* __restrict__ x,   // [128,3,224,224]
                        ushort* __restrict__ x4) {
    int t = blockIdx.x * 256 + threadIdx.x;
    if (t >= 128 * 51076) return;
    int b = t / 51076, pix = t % 51076;
    int Y = pix / 226, X = pix % 226;
    ushort pk[4] = {0, 0, 0, 0};
    if (Y >= 1 && Y <= 224 && X >= 1 && X <= 224) {
        const float* xb = x + ((size_t)b * 3) * 50176 + (Y - 1) * 224 + (X - 1);
        pk[0] = f2bf(xb[0]);
        pk[1] = f2bf(xb[50176]);
        pk[2] = f2bf(xb[100352]);
    }
    *(short4v*)&x4[(size_t)t * 4] = *(const short4v*)pk;
}

// ---------------- weight-fragment prep (sgn -> bf16, MFMA fragment order) -------
__global__ void wfrag_prep(const float* __restrict__ w2, const float* __restrict__ w3,
                           const float* __restrict__ w1,
                           ushort* __restrict__ f2, ushort* __restrict__ f3,
                           ushort* __restrict__ f1) {
    int t = blockIdx.x * 256 + threadIdx.x;
    if (t < 5120) {
        int j = t & 7, l = (t >> 3) & 63, nc = t >> 9;  // nc = c*2 + n
        int n = nc & 1, c = nc >> 1;
        int k = c * 32 + ((l >> 4) << 3) + j;
        ushort v = 0;
        if (k < 144) {
            int ky = k / 48, rem = k % 48, kx = rem >> 4, ci = rem & 15;
            int co = n * 16 + (l & 15);
            v = sgn2bf(w2[((co * 16 + ci) * 3 + ky) * 3 + kx]);
        }
        f2[t] = v;
    } else if (t < 23552) {
        int t2 = t - 5120;
        int j = t2 & 7, l = (t2 >> 3) & 63, nc = t2 >> 9;  // nc = c*4 + n
        int n = nc & 3, c = nc >> 2;
        int k = c * 32 + ((l >> 4) << 3) + j;               // < 288
        int ky = k / 96, rem = k % 96, kx = rem >> 5, ci = rem & 31;
        int co = n * 16 + (l & 15);
        f3[t2] = sgn2bf(w3[((co * 32 + ci) * 3 + ky) * 3 + kx]);
    } else {
        int t1 = t - 23552;
        if (t1 >= 1024) return;
        int j = t1 & 7, l = (t1 >> 3) & 63, c = t1 >> 9;    // c = 0,1
        int k = c * 32 + ((l >> 4) << 3) + j;               // 0..63
        int ky = k >> 4, kx = (k >> 2) & 3, ci = k & 3;
        ushort v = 0;
        if (ky < 3 && kx < 3 && ci < 3) {
            int co = l & 15;
            v = sgn2bf(w1[((co * 3 + ci) * 3 + ky) * 3 + kx]);
        }
        f1[t1] = v;
    }
}

// ---------------- wf1_prep_t: wf1 fp32 [128][50176] -> sign bf16, K-permuted ----
__global__ void wf1_prep_t(const float* __restrict__ wf1, ushort* __restrict__ wsg) {
    const int pt  = blockIdx.x;      // 0..6
    const int co2 = blockIdx.y;      // 0..127
    __shared__ ushort T[64][114];
#pragma unroll
    for (int k = 0; k < 7; ++k) {
        int i = threadIdx.x + k * 256;      // 0..1791 over [64 co][28 p-float4]
        int co = i / 28, pf = i % 28;
        const float4 v = *(const float4*)&wf1[(size_t)co2 * 50176 + co * 784 + pt * 112 + pf * 4];
        T[co][pf * 4 + 0] = sgn2bf(v.x);
        T[co][pf * 4 + 1] = sgn2bf(v.y);
        T[co][pf * 4 + 2] = sgn2bf(v.z);
        T[co][pf * 4 + 3] = sgn2bf(v.w);
    }
    __syncthreads();
#pragma unroll
    for (int k = 0; k < 7; ++k) {
        int j = threadIdx.x + k * 256;      // 0..1791 over [112 p][16 co-groups]
        int p = j >> 4, cg = j & 15;
        ushort pk[4] = {T[cg * 4 + 0][p], T[cg * 4 + 1][p], T[cg * 4 + 2][p], T[cg * 4 + 3][p]};
        *(short4v*)&wsg[(size_t)co2 * 50176 + (size_t)(pt * 112 + p) * 64 + cg * 4] =
            *(const short4v*)pk;
    }
}

// ---------------- conv1: MFMA im2col, quad A-rows, register maxpool -------------
// (unchanged from round 9; co=16 cannot be co-paired)
__global__ __launch_bounds__(256) void
conv1_mfma(const ushort* __restrict__ x4,    // [128,226,226,4] bf16
           const ushort* __restrict__ wfrag, // [2][64][8] bf16
           const float* __restrict__ bias,   // [16]
           ushort* __restrict__ h1p) {       // [128,114,114,16] bf16
    const int py = blockIdx.x;               // pooled row 0..111
    const int b  = blockIdx.z;
    const int wv = threadIdx.x >> 6, l = threadIdx.x & 63;
    const int lhi = l >> 4, llo = l & 15;
    const int q = llo >> 2, e = llo & 3;
    const int xpre0 = wv * 56 + 2 * q + (e & 1);
    const int ypre  = 2 * py + (e >> 1);

    short8 wf[2];
#pragma unroll
    for (int c = 0; c < 2; ++c)
        wf[c] = *(const short8*)&wfrag[(c * 64 + l) * 8];
    const float bv = bias[llo];

    const ushort* ptr[2]; bool vld[2];
#pragma unroll
    for (int c = 0; c < 2; ++c) {
        const int cc = c * 4 + lhi, ky = cc >> 1, half = cc & 1;
        vld[c] = (ky < 3);
        const int kyc = vld[c] ? ky : 0;
        ptr[c] = &x4[(((size_t)(b * 226 + ypre + kyc)) * 226 + xpre0 + 2 * half) * 4];
    }

    short8 a[7][2];
#pragma unroll
    for (int i = 0; i < 7; ++i)
#pragma unroll
        for (int c = 0; c < 2; ++c) {
            short8 t = {};
            if (vld[c]) t = (short8)(*(const short8u*)(ptr[c] + i * 32));
            a[i][c] = t;
        }

    f32x4 acc[7];
#pragma unroll
    for (int i = 0; i < 7; ++i) acc[i] = (f32x4){0.f, 0.f, 0.f, 0.f};
#pragma unroll
    for (int i = 0; i < 7; ++i)
#pragma unroll
        for (int c = 0; c < 2; ++c)
            acc[i] = __builtin_amdgcn_mfma_f32_16x16x32_bf16(a[i][c], wf[c], acc[i], 0, 0, 0);

    const size_t obase = ((size_t)(b * 114 + 1 + py) * 114 + 1) * 16 + llo;
#pragma unroll
    for (int i = 0; i < 7; ++i) {
        float v = fmaxf(fmaxf(acc[i][0], acc[i][1]), fmaxf(acc[i][2], acc[i][3]));
        v = fmaxf(v + bv, 0.f);
        h1p[obase + (size_t)(wv * 28 + i * 4 + lhi) * 16] = f2bf(v);
    }
}

// ---------------- conv2: MFMA im2col, wave owns ALL 32 co (2 co-tiles) ----------
// grid (28, 1, 128), block 256 = 4 waves: wave = (mh = wv>>1 x-half, r = wv&1 py)
// Per wave: 35 A-loads feed 70 MFMAs (2x fewer loads/MFMA than round 9).
__global__ __launch_bounds__(256, 2) void
conv2_mfma(const ushort* __restrict__ h1p,   // [128,114,114,16] bf16
           const ushort* __restrict__ wfrag, // [5][2][64][8] bf16
           const float* __restrict__ bias,   // [32]
           ushort* __restrict__ h2p) {       // [128,58,58,32] bf16
    const int b  = blockIdx.z;
    const int wv = threadIdx.x >> 6, l = threadIdx.x & 63;
    const int mh = wv >> 1, r = wv & 1;
    const int py = blockIdx.x * 2 + r;       // pooled row 0..55
    const int lhi = l >> 4, llo = l & 15;
    const int q = llo >> 2, e = llo & 3;
    const int xpre0 = mh * 56 + 2 * q + (e & 1);
    const int ypre  = 2 * py + (e >> 1);

    short8 wf[5][2];
#pragma unroll
    for (int c = 0; c < 5; ++c)
#pragma unroll
        for (int n = 0; n < 2; ++n)
            wf[c][n] = *(const short8*)&wfrag[(((c * 2 + n) * 64) + l) * 8];
    const float bv0 = bias[llo], bv1 = bias[16 + llo];

    const ushort* ptr[5]; bool vld[5];
#pragma unroll
    for (int c = 0; c < 5; ++c) {
        const int cc = c * 4 + lhi;          // 0..19, valid < 18
        vld[c] = (cc < 18);
        const int dy = vld[c] ? (cc / 6) : 0;
        const int koff = (cc % 6) * 8;
        ptr[c] = &h1p[(((size_t)(b * 114 + ypre + dy)) * 114 + xpre0) * 16 + koff];
    }

    f32x4 acc[7][2];
#pragma unroll
    for (int m = 0; m < 7; ++m)
#pragma unroll
        for (int n = 0; n < 2; ++n) acc[m][n] = (f32x4){0.f, 0.f, 0.f, 0.f};

#pragma unroll
    for (int c = 0; c < 5; ++c) {
        short8 a[7];
#pragma unroll
        for (int m = 0; m < 7; ++m) {
            short8 t = {};
            if (vld[c]) t = *(const short8*)(ptr[c] + m * 128);
            a[m] = t;
        }
#pragma unroll
        for (int m = 0; m < 7; ++m) {
            acc[m][0] = __builtin_amdgcn_mfma_f32_16x16x32_bf16(a[m], wf[c][0], acc[m][0], 0, 0, 0);
            acc[m][1] = __builtin_amdgcn_mfma_f32_16x16x32_bf16(a[m], wf[c][1], acc[m][1], 0, 0, 0);
        }
    }

    const size_t obase = ((size_t)(b * 58 + 1 + py) * 58 + 1) * 32 + llo;
#pragma unroll
    for (int m = 0; m < 7; ++m) {
        const size_t po = obase + (size_t)(mh * 28 + m * 4 + lhi) * 32;
        float v0 = fmaxf(fmaxf(acc[m][0][0], acc[m][0][1]), fmaxf(acc[m][0][2], acc[m][0][3]));
        h2p[po]      = f2bf(fmaxf(v0 + bv0, 0.f));
        float v1 = fmaxf(fmaxf(acc[m][1][0], acc[m][1][1]), fmaxf(acc[m][1][2], acc[m][1][3]));
        h2p[po + 16] = f2bf(fmaxf(v1 + bv1, 0.f));
    }
}

// ---------------- conv3: MFMA im2col, wave owns ALL 64 co (4 co-tiles) ----------
// grid (7, 1, 128), block 256 = 4 waves: wave wv -> pooled row py = bx*4+wv.
// Per wave: 63 A-loads + 36 streamed wf-loads feed 252 MFMAs (4x fewer A-loads).
__global__ __launch_bounds__(256, 2) void
conv3_mfma(const ushort* __restrict__ h2p,   // [128,58,58,32] bf16
           const ushort* __restrict__ wfrag, // [9][4][64][8] bf16
           const float* __restrict__ bias,   // [64]
           ushort* __restrict__ h3b) {       // [128][50176] bf16 (p*64+co)
    const int b  = blockIdx.z;
    const int wv = threadIdx.x >> 6, l = threadIdx.x & 63;
    const int py = blockIdx.x * 4 + wv;      // pooled row 0..27
    const int lhi = l >> 4, llo = l & 15;
    const int q = llo >> 2, e = llo & 3;
    const int xpre0 = 2 * q + (e & 1);
    const int ypre  = 2 * py + (e >> 1);

    const float bv[4] = {bias[llo], bias[16 + llo], bias[32 + llo], bias[48 + llo]};

    const ushort* ptr[9];
#pragma unroll
    for (int c = 0; c < 9; ++c) {
        const int cc = c * 4 + lhi;          // 0..35, all valid
        const int dy = cc / 12, koff = (cc % 12) * 8;
        ptr[c] = &h2p[(((size_t)(b * 58 + ypre + dy)) * 58 + xpre0) * 32 + koff];
    }

    f32x4 acc[7][4];
#pragma unroll
    for (int m = 0; m < 7; ++m)
#pragma unroll
        for (int n = 0; n < 4; ++n) acc[m][n] = (f32x4){0.f, 0.f, 0.f, 0.f};

#pragma unroll
    for (int c = 0; c < 9; ++c) {
        // stream this k-step's 4 weight fragments (not resident: saves ~128 VGPR)
        const short8 wf0 = *(const short8*)&wfrag[(((c * 4 + 0) * 64) + l) * 8];
        const short8 wf1 = *(const short8*)&wfrag[(((c * 4 + 1) * 64) + l) * 8];
        const short8 wf2 = *(const short8*)&wfrag[(((c * 4 + 2) * 64) + l) * 8];
        const short8 wf3 = *(const short8*)&wfrag[(((c * 4 + 3) * 64) + l) * 8];
        short8 a[7];
#pragma unroll
        for (int m = 0; m < 7; ++m)
            a[m] = *(const short8*)(ptr[c] + m * 256);
#pragma unroll
        for (int m = 0; m < 7; ++m) {
            acc[m][0] = __builtin_amdgcn_mfma_f32_16x16x32_bf16(a[m], wf0, acc[m][0], 0, 0, 0);
            acc[m][1] = __builtin_amdgcn_mfma_f32_16x16x32_bf16(a[m], wf1, acc[m][1], 0, 0, 0);
            acc[m][2] = __builtin_amdgcn_mfma_f32_16x16x32_bf16(a[m], wf2, acc[m][2], 0, 0, 0);
            acc[m][3] = __builtin_amdgcn_mfma_f32_16x16x32_bf16(a[m], wf3, acc[m][3], 0, 0, 0);
        }
    }

    const size_t obase = (size_t)b * 50176 + (size_t)(py * 28) * 64 + llo;
#pragma unroll
    for (int m = 0; m < 7; ++m) {
        const size_t po = obase + (size_t)(m * 4 + lhi) * 64;
#pragma unroll
        for (int n = 0; n < 4; ++n) {
            float v = fmaxf(fmaxf(acc[m][n][0], acc[m][n][1]),
                            fmaxf(acc[m][n][2], acc[m][n][3]));
            v = fmaxf(v + bv[n], 0.f);
            h3b[po + n * 16] = f2bf(v);
        }
    }
}

// ---------------- FC1 stage A: bf16 MFMA split-K GEMM ---------------------------
__global__ __launch_bounds__(256) void
fc1_mfmaA(const ushort* __restrict__ actb,  // [128][50176] bf16 (K-permuted)
          const ushort* __restrict__ wsg,   // [128][50176] bf16 (same K-perm)
          float* __restrict__ partials) {   // [49][128][128]
    const int K = 50176;
    const int bt = blockIdx.x * 32, ct = blockIdx.y * 32, ks = blockIdx.z;
    const int wv = threadIdx.x >> 6, l = threadIdx.x & 63;
    const int lhi = l >> 4, llo = l & 15;

    __shared__ float lds[4][32][33];

    f32x4 acc[2][2];
#pragma unroll
    for (int i = 0; i < 2; ++i)
#pragma unroll
        for (int j = 0; j < 2; ++j) acc[i][j] = (f32x4){0.f, 0.f, 0.f, 0.f};

    const int kw = ks * 1024 + wv * 256 + lhi * 8;
    const ushort* a0p = actb + (size_t)(bt + llo)      * K + kw;
    const ushort* a1p = actb + (size_t)(bt + llo + 16) * K + kw;
    const ushort* b0p = wsg  + (size_t)(ct + llo)      * K + kw;
    const ushort* b1p = wsg  + (size_t)(ct + llo + 16) * K + kw;

#pragma unroll
    for (int s = 0; s < 8; ++s) {
        const int off = s * 32;
        const short8 a0 = *(const short8*)(a0p + off);
        const short8 a1 = *(const short8*)(a1p + off);
        const short8 b0 = *(const short8*)(b0p + off);
        const short8 b1 = *(const short8*)(b1p + off);
        acc[0][0] = __builtin_amdgcn_mfma_f32_16x16x32_bf16(a0, b0, acc[0][0], 0, 0, 0);
        acc[0][1] = __builtin_amdgcn_mfma_f32_16x16x32_bf16(a0, b1, acc[0][1], 0, 0, 0);
        acc[1][0] = __builtin_amdgcn_mfma_f32_16x16x32_bf16(a1, b0, acc[1][0], 0, 0, 0);
        acc[1][1] = __builtin_amdgcn_mfma_f32_16x16x32_bf16(a1, b1, acc[1][1], 0, 0, 0);
    }

#pragma unroll
    for (int i = 0; i < 2; ++i)
#pragma unroll
        for (int jj = 0; jj < 2; ++jj)
#pragma unroll
            for (int j = 0; j < 4; ++j)
                lds[wv][i * 16 + lhi * 4 + j][jj * 16 + llo] = acc[i][jj][j];
    __syncthreads();

    float* pb = partials + (size_t)ks * 16384;
#pragma unroll
    for (int u = 0; u < 4; ++u) {
        int idx = threadIdx.x + u * 256;     // 0..1023
        int m = idx >> 5, n = idx & 31;
        float v = lds[0][m][n] + lds[1][m][n] + lds[2][m][n] + lds[3][m][n];
        pb[(bt + m) * 128 + ct + n] = v;
    }
}

// ---------------- FC1 stage B: reduce 49 partials + bias + relu -----------------
__global__ void fc1_stageB(const float* __restrict__ partials,
                           const float* __restrict__ bf,
                           float* __restrict__ f1) {
    const int o = blockIdx.x * 256 + threadIdx.x;  // 0..16383
    float acc = 0.f;
    for (int ks = 0; ks < 49; ++ks) acc += partials[(size_t)ks * 16384 + o];
    f1[o] = fmaxf(acc + bf[o & 127], 0.f);
}

// ---------------- FC2 ------------------------------------------------------------
__global__ void fc2_kernel(const float* __restrict__ act,
                           const float* __restrict__ wf,
                           const float* __restrict__ bf,
                           float* __restrict__ out) {
    const int o = blockIdx.x * 256 + threadIdx.x;
    if (o >= 128 * 1000) return;
    const int b = o / 1000, co = o % 1000;
    const float* a  = act + b * 128;
    const float* wr = wf + co * 128;
    float acc = 0.f;
#pragma unroll 8
    for (int k = 0; k < 128; ++k)
        acc = fmaf(a[k], sgn(wr[k]), acc);
    out[o] = acc + bf[co];
}

extern "C" void kernel_launch(void* const* d_in, const int* in_sizes, int n_in,
                              void* d_out, int out_size, void* d_ws, size_t ws_size,
                              hipStream_t stream) {
    const float* x   = (const float*)d_in[0];
    const float* w1  = (const float*)d_in[1];
    const float* b1  = (const float*)d_in[2];
    const float* w2  = (const float*)d_in[3];
    const float* b2  = (const float*)d_in[4];
    const float* w3  = (const float*)d_in[5];
    const float* b3  = (const float*)d_in[6];
    const float* wf1 = (const float*)d_in[7];
    const float* bf1 = (const float*)d_in[8];
    const float* wf2 = (const float*)d_in[9];
    const float* bf2 = (const float*)d_in[10];

    // ws layout (peak 133.1 MB):
    //   h1p bf16 [128,114,114,16] @ 0            (53,231,616)
    //   x4  bf16 [128,226,226,4]  @ 53,231,616   (52,276,224)  dead after conv1
    //     overlaid on dead x4:
    //     h3b  bf16 [128][50176]  @ 53,231,616   (12,845,056)  NHWC-permuted K
    //     wsg1 bf16 [128][50176]  @ 66,076,672   (12,845,056)  same K-perm
    //     pa   fp32 [49][16384]   @ 78,921,728   ( 3,211,264)
    //     f1   fp32 [128,128]     @ 82,132,992   (    65,536)
    //   h2p bf16 [128,58,58,32]   @ 105,507,840  (27,557,888)
    //   wf1frag @ 133,065,728 (2,048); wf2frag @ 133,067,776 (10,240);
    //   wf3frag @ 133,078,016 (36,864)
    char* ws = (char*)d_ws;
    ushort* h1p  = (ushort*)ws;
    ushort* x4   = (ushort*)(ws + 53231616u);
    ushort* h3b  = (ushort*)(ws + 53231616u);
    ushort* wsg1 = (ushort*)(ws + 66076672u);
    float*  pa   = (float*) (ws + 78921728u);
    float*  f1   = (float*) (ws + 82132992u);
    ushort* h2p  = (ushort*)(ws + 105507840u);
    ushort* wf1frag = (ushort*)(ws + 133065728u);
    ushort* wf2frag = (ushort*)(ws + 133067776u);
    ushort* wf3frag = (ushort*)(ws + 133078016u);

    pad_zero<<<7265, 256, 0, stream>>>(h1p, h2p);
    wfrag_prep<<<96, 256, 0, stream>>>(w2, w3, w1, wf2frag, wf3frag, wf1frag);
    x4_prep<<<25538, 256, 0, stream>>>(x, x4);
    conv1_mfma<<<dim3(112, 1, 128), 256, 0, stream>>>(x4, wf1frag, b1, h1p);
    // x4 now dead; regions overlaying it may be written from here on
    wf1_prep_t<<<dim3(7, 128), 256, 0, stream>>>(wf1, wsg1);
    conv2_mfma<<<dim3(28, 1, 128), 256, 0, stream>>>(h1p, wf2frag, b2, h2p);
    conv3_mfma<<<dim3(7, 1, 128), 256, 0, stream>>>(h2p, wf3frag, b3, h3b);
    fc1_mfmaA<<<dim3(4, 4, 49), 256, 0, stream>>>(h3b, wsg1, pa);
    fc1_stageB<<<64, 256, 0, stream>>>(pa, bf1, f1);
    fc2_kernel<<<500, 256, 0, stream>>>(f1, wf2, bf2, (float*)d_out);
}

// Round 11
// 140.753 us; speedup vs baseline: 35.7075x; 1.2470x over previous
//
#include <hip/hip_runtime.h>

typedef __attribute__((ext_vector_type(8))) short short8;
typedef __attribute__((ext_vector_type(8), aligned(8))) short short8u;  // 8B-aligned 16B load
typedef __attribute__((ext_vector_type(4))) short short4v;
typedef __attribute__((ext_vector_type(4))) float f32x4;
typedef unsigned short ushort;
typedef unsigned int uint;

static __device__ __forceinline__ float sgn(float v) {
    return (v > 0.f) ? 1.f : ((v < 0.f) ? -1.f : 0.f);
}
static __device__ __forceinline__ ushort f2bf(float f) {
    uint u = __builtin_bit_cast(uint, f);
    u += 0x7fffu + ((u >> 16) & 1u);   // RNE
    return (ushort)(u >> 16);
}
static __device__ __forceinline__ ushort sgn2bf(float v) {
    return (v > 0.f) ? (ushort)0x3F80 : ((v < 0.f) ? (ushort)0xBF80 : (ushort)0);
}

// ---------------- pad-zero: zero the halo borders of h1p and h2p ----------------
__global__ void pad_zero(ushort* __restrict__ h1p, ushort* __restrict__ h2p) {
    int t = blockIdx.x * 256 + threadIdx.x;
    if (t < 925696) {                       // h1p: 128 b x 452 cells x 16 ch
        int b = t / 7232, r = t % 7232;
        int cell = r >> 4, ch = r & 15;
        int y, x;
        if (cell < 114)      { y = 0;   x = cell; }
        else if (cell < 228) { y = 113; x = cell - 114; }
        else { int s = cell - 228; y = 1 + (s >> 1); x = (s & 1) ? 113 : 0; }
        h1p[((b * 114 + y) * 114 + x) * 16 + ch] = 0;
    } else {
        t -= 925696;
        if (t >= 933888) return;            // h2p: 128 b x 228 cells x 32 ch
        int b = t / 7296, r = t % 7296;
        int cell = r >> 5, ch = r & 31;
        int y, x;
        if (cell < 58)       { y = 0;  x = cell; }
        else if (cell < 116) { y = 57; x = cell - 58; }
        else { int s = cell - 116; y = 1 + (s >> 1); x = (s & 1) ? 57 : 0; }
        h2p[((b * 58 + y) * 58 + x) * 32 + ch] = 0;
    }
}

// ---------------- weight-fragment prep (sgn -> bf16, MFMA fragment order) -------
__global__ void wfrag_prep(const float* __restrict__ w2, const float* __restrict__ w3,
                           const float* __restrict__ w1,
                           ushort* __restrict__ f2, ushort* __restrict__ f3,
                           ushort* __restrict__ f1) {
    int t = blockIdx.x * 256 + threadIdx.x;
    if (t < 5120) {
        int j = t & 7, l = (t >> 3) & 63, nc = t >> 9;  // nc = c*2 + n
        int n = nc & 1, c = nc >> 1;
        int k = c * 32 + ((l >> 4) << 3) + j;
        ushort v = 0;
        if (k < 144) {
            int ky = k / 48, rem = k % 48, kx = rem >> 4, ci = rem & 15;
            int co = n * 16 + (l & 15);
            v = sgn2bf(w2[((co * 16 + ci) * 3 + ky) * 3 + kx]);
        }
        f2[t] = v;
    } else if (t < 23552) {
        int t2 = t - 5120;
        int j = t2 & 7, l = (t2 >> 3) & 63, nc = t2 >> 9;  // nc = c*4 + n
        int n = nc & 3, c = nc >> 2;
        int k = c * 32 + ((l >> 4) << 3) + j;               // < 288
        int ky = k / 96, rem = k % 96, kx = rem >> 5, ci = rem & 31;
        int co = n * 16 + (l & 15);
        f3[t2] = sgn2bf(w3[((co * 32 + ci) * 3 + ky) * 3 + kx]);
    } else {
        int t1 = t - 23552;
        if (t1 >= 1024) return;
        int j = t1 & 7, l = (t1 >> 3) & 63, c = t1 >> 9;    // c = 0,1
        int k = c * 32 + ((l >> 4) << 3) + j;               // 0..63
        int ky = k >> 4, kx = (k >> 2) & 3, ci = k & 3;
        ushort v = 0;
        if (ky < 3 && kx < 3 && ci < 3) {
            int co = l & 15;
            v = sgn2bf(w1[((co * 3 + ci) * 3 + ky) * 3 + kx]);
        }
        f1[t1] = v;
    }
}

// ---------------- wf1_prep_t: wf1 fp32 [128][50176] -> sign bf16, K-permuted ----
__global__ void wf1_prep_t(const float* __restrict__ wf1, ushort* __restrict__ wsg) {
    const int pt  = blockIdx.x;      // 0..6
    const int co2 = blockIdx.y;      // 0..127
    __shared__ ushort T[64][114];
#pragma unroll
    for (int k = 0; k < 7; ++k) {
        int i = threadIdx.x + k * 256;      // 0..1791 over [64 co][28 p-float4]
        int co = i / 28, pf = i % 28;
        const float4 v = *(const float4*)&wf1[(size_t)co2 * 50176 + co * 784 + pt * 112 + pf * 4];
        T[co][pf * 4 + 0] = sgn2bf(v.x);
        T[co][pf * 4 + 1] = sgn2bf(v.y);
        T[co][pf * 4 + 2] = sgn2bf(v.z);
        T[co][pf * 4 + 3] = sgn2bf(v.w);
    }
    __syncthreads();
#pragma unroll
    for (int k = 0; k < 7; ++k) {
        int j = threadIdx.x + k * 256;      // 0..1791 over [112 p][16 co-groups]
        int p = j >> 4, cg = j & 15;
        ushort pk[4] = {T[cg * 4 + 0][p], T[cg * 4 + 1][p], T[cg * 4 + 2][p], T[cg * 4 + 3][p]};
        *(short4v*)&wsg[(size_t)co2 * 50176 + (size_t)(pt * 112 + p) * 64 + cg * 4] =
            *(const short4v*)pk;
    }
}

// ---------------- conv1: FUSED x-prep + MFMA im2col via LDS staging -------------
// Block = one pooled row: stages 4 fp32 input rows (3ch) -> bf16 4ch LDS (7.2KB),
// then quad-layout A-fragments come from LDS (no global gathers, no x4 pass).
__global__ __launch_bounds__(256) void
conv1_fused(const float* __restrict__ x,     // [128,3,224,224] fp32
            const ushort* __restrict__ wfrag,// [2][64][8] bf16
            const float* __restrict__ bias,  // [16]
            ushort* __restrict__ h1p) {      // [128,114,114,16] bf16
    const int py = blockIdx.x;               // pooled row 0..111
    const int b  = blockIdx.z;

    __shared__ ushort lx[4][226][4];         // 4 input rows, padded cols, 4ch bf16

    // ---- stage ----
    {
        const int t = threadIdx.x;
        if (t < 224) {
            const int r = t / 56, p4 = (t % 56) * 4;   // row 0..3, cols p4..p4+3
            const int row = 2 * py - 1 + r;
            float4 v0 = {0,0,0,0}, v1 = {0,0,0,0}, v2 = {0,0,0,0};
            if ((unsigned)row < 224u) {
                const float* xb = x + (((size_t)b * 3) * 224 + row) * 224 + p4;
                v0 = *(const float4*)(xb);
                v1 = *(const float4*)(xb + 50176);
                v2 = *(const float4*)(xb + 100352);
            }
            const float c0[4] = {v0.x, v0.y, v0.z, v0.w};
            const float c1[4] = {v1.x, v1.y, v1.z, v1.w};
            const float c2[4] = {v2.x, v2.y, v2.z, v2.w};
#pragma unroll
            for (int j = 0; j < 4; ++j) {
                ushort pk[4] = {f2bf(c0[j]), f2bf(c1[j]), f2bf(c2[j]), 0};
                *(short4v*)&lx[r][1 + p4 + j][0] = *(const short4v*)pk;
            }
        } else if (t < 232) {
            const int s = t - 224, r = s >> 1, col = (s & 1) ? 225 : 0;
            ushort pk[4] = {0, 0, 0, 0};
            *(short4v*)&lx[r][col][0] = *(const short4v*)pk;
        }
    }
    __syncthreads();

    const int wv = threadIdx.x >> 6, l = threadIdx.x & 63;
    const int lhi = l >> 4, llo = l & 15;
    const int q = llo >> 2, e = llo & 3;
    const int xl0 = wv * 56 + 2 * q + (e & 1);   // padded col base
    const int r0  = e >> 1;

    short8 wf[2];
#pragma unroll
    for (int c = 0; c < 2; ++c)
        wf[c] = *(const short8*)&wfrag[(c * 64 + l) * 8];
    const float bv = bias[llo];

    const ushort* lptr[2]; bool vld[2];
#pragma unroll
    for (int c = 0; c < 2; ++c) {
        const int cc = c * 4 + lhi, ky = cc >> 1, half = cc & 1;
        vld[c] = (ky < 3);
        const int kyc = vld[c] ? ky : 0;
        lptr[c] = &lx[r0 + kyc][xl0 + 2 * half][0];
    }

    f32x4 acc[7];
#pragma unroll
    for (int i = 0; i < 7; ++i) acc[i] = (f32x4){0.f, 0.f, 0.f, 0.f};

#pragma unroll
    for (int i = 0; i < 7; ++i)
#pragma unroll
        for (int c = 0; c < 2; ++c) {
            short8 a = {};
            if (vld[c]) a = (short8)(*(const short8u*)(lptr[c] + i * 32));
            acc[i] = __builtin_amdgcn_mfma_f32_16x16x32_bf16(a, wf[c], acc[i], 0, 0, 0);
        }

    const size_t obase = ((size_t)(b * 114 + 1 + py) * 114 + 1) * 16 + llo;
#pragma unroll
    for (int i = 0; i < 7; ++i) {
        float v = fmaxf(fmaxf(acc[i][0], acc[i][1]), fmaxf(acc[i][2], acc[i][3]));
        v = fmaxf(v + bv, 0.f);
        h1p[obase + (size_t)(wv * 28 + i * 4 + lhi) * 16] = f2bf(v);
    }
}

// ---------------- conv2: MFMA im2col, wave owns ALL 32 co (2 co-tiles) ----------
__global__ __launch_bounds__(256, 2) void
conv2_mfma(const ushort* __restrict__ h1p,   // [128,114,114,16] bf16
           const ushort* __restrict__ wfrag, // [5][2][64][8] bf16
           const float* __restrict__ bias,   // [32]
           ushort* __restrict__ h2p) {       // [128,58,58,32] bf16
    const int b  = blockIdx.z;
    const int wv = threadIdx.x >> 6, l = threadIdx.x & 63;
    const int mh = wv >> 1, r = wv & 1;
    const int py = blockIdx.x * 2 + r;       // pooled row 0..55
    const int lhi = l >> 4, llo = l & 15;
    const int q = llo >> 2, e = llo & 3;
    const int xpre0 = mh * 56 + 2 * q + (e & 1);
    const int ypre  = 2 * py + (e >> 1);

    short8 wf[5][2];
#pragma unroll
    for (int c = 0; c < 5; ++c)
#pragma unroll
        for (int n = 0; n < 2; ++n)
            wf[c][n] = *(const short8*)&wfrag[(((c * 2 + n) * 64) + l) * 8];
    const float bv0 = bias[llo], bv1 = bias[16 + llo];

    const ushort* ptr[5]; bool vld[5];
#pragma unroll
    for (int c = 0; c < 5; ++c) {
        const int cc = c * 4 + lhi;          // 0..19, valid < 18
        vld[c] = (cc < 18);
        const int dy = vld[c] ? (cc / 6) : 0;
        const int koff = (cc % 6) * 8;
        ptr[c] = &h1p[(((size_t)(b * 114 + ypre + dy)) * 114 + xpre0) * 16 + koff];
    }

    f32x4 acc[7][2];
#pragma unroll
    for (int m = 0; m < 7; ++m)
#pragma unroll
        for (int n = 0; n < 2; ++n) acc[m][n] = (f32x4){0.f, 0.f, 0.f, 0.f};

#pragma unroll
    for (int c = 0; c < 5; ++c) {
        short8 a[7];
#pragma unroll
        for (int m = 0; m < 7; ++m) {
            short8 t = {};
            if (vld[c]) t = *(const short8*)(ptr[c] + m * 128);
            a[m] = t;
        }
#pragma unroll
        for (int m = 0; m < 7; ++m) {
            acc[m][0] = __builtin_amdgcn_mfma_f32_16x16x32_bf16(a[m], wf[c][0], acc[m][0], 0, 0, 0);
            acc[m][1] = __builtin_amdgcn_mfma_f32_16x16x32_bf16(a[m], wf[c][1], acc[m][1], 0, 0, 0);
        }
    }

    const size_t obase = ((size_t)(b * 58 + 1 + py) * 58 + 1) * 32 + llo;
#pragma unroll
    for (int m = 0; m < 7; ++m) {
        const size_t po = obase + (size_t)(mh * 28 + m * 4 + lhi) * 32;
        float v0 = fmaxf(fmaxf(acc[m][0][0], acc[m][0][1]), fmaxf(acc[m][0][2], acc[m][0][3]));
        h2p[po]      = f2bf(fmaxf(v0 + bv0, 0.f));
        float v1 = fmaxf(fmaxf(acc[m][1][0], acc[m][1][1]), fmaxf(acc[m][1][2], acc[m][1][3]));
        h2p[po + 16] = f2bf(fmaxf(v1 + bv1, 0.f));
    }
}

// ---------------- conv3: MFMA im2col, wave owns ALL 64 co (4 co-tiles) ----------
__global__ __launch_bounds__(256, 2) void
conv3_mfma(const ushort* __restrict__ h2p,   // [128,58,58,32] bf16
           const ushort* __restrict__ wfrag, // [9][4][64][8] bf16
           const float* __restrict__ bias,   // [64]
           ushort* __restrict__ h3b) {       // [128][50176] bf16 (p*64+co)
    const int b  = blockIdx.z;
    const int wv = threadIdx.x >> 6, l = threadIdx.x & 63;
    const int py = blockIdx.x * 4 + wv;      // pooled row 0..27
    const int lhi = l >> 4, llo = l & 15;
    const int q = llo >> 2, e = llo & 3;
    const int xpre0 = 2 * q + (e & 1);
    const int ypre  = 2 * py + (e >> 1);

    const float bv[4] = {bias[llo], bias[16 + llo], bias[32 + llo], bias[48 + llo]};

    const ushort* ptr[9];
#pragma unroll
    for (int c = 0; c < 9; ++c) {
        const int cc = c * 4 + lhi;          // 0..35, all valid
        const int dy = cc / 12, koff = (cc % 12) * 8;
        ptr[c] = &h2p[(((size_t)(b * 58 + ypre + dy)) * 58 + xpre0) * 32 + koff];
    }

    f32x4 acc[7][4];
#pragma unroll
    for (int m = 0; m < 7; ++m)
#pragma unroll
        for (int n = 0; n < 4; ++n) acc[m][n] = (f32x4){0.f, 0.f, 0.f, 0.f};

#pragma unroll
    for (int c = 0; c < 9; ++c) {
        const short8 wf0 = *(const short8*)&wfrag[(((c * 4 + 0) * 64) + l) * 8];
        const short8 wf1 = *(const short8*)&wfrag[(((c * 4 + 1) * 64) + l) * 8];
        const short8 wf2 = *(const short8*)&wfrag[(((c * 4 + 2) * 64) + l) * 8];
        const short8 wf3 = *(const short8*)&wfrag[(((c * 4 + 3) * 64) + l) * 8];
        short8 a[7];
#pragma unroll
        for (int m = 0; m < 7; ++m)
            a[m] = *(const short8*)(ptr[c] + m * 256);
#pragma unroll
        for (int m = 0; m < 7; ++m) {
            acc[m][0] = __builtin_amdgcn_mfma_f32_16x16x32_bf16(a[m], wf0, acc[m][0], 0, 0, 0);
            acc[m][1] = __builtin_amdgcn_mfma_f32_16x16x32_bf16(a[m], wf1, acc[m][1], 0, 0, 0);
            acc[m][2] = __builtin_amdgcn_mfma_f32_16x16x32_bf16(a[m], wf2, acc[m][2], 0, 0, 0);
            acc[m][3] = __builtin_amdgcn_mfma_f32_16x16x32_bf16(a[m], wf3, acc[m][3], 0, 0, 0);
        }
    }

    const size_t obase = (size_t)b * 50176 + (size_t)(py * 28) * 64 + llo;
#pragma unroll
    for (int m = 0; m < 7; ++m) {
        const size_t po = obase + (size_t)(m * 4 + lhi) * 64;
#pragma unroll
        for (int n = 0; n < 4; ++n) {
            float v = fmaxf(fmaxf(acc[m][n][0], acc[m][n][1]),
                            fmaxf(acc[m][n][2], acc[m][n][3]));
            v = fmaxf(v + bv[n], 0.f);
            h3b[po + n * 16] = f2bf(v);
        }
    }
}

// ---------------- FC1 stage A: bf16 MFMA split-K GEMM ---------------------------
__global__ __launch_bounds__(256) void
fc1_mfmaA(const ushort* __restrict__ actb,  // [128][50176] bf16 (K-permuted)
          const ushort* __restrict__ wsg,   // [128][50176] bf16 (same K-perm)
          float* __restrict__ partials) {   // [49][128][128]
    const int K = 50176;
    const int bt = blockIdx.x * 32, ct = blockIdx.y * 32, ks = blockIdx.z;
    const int wv = threadIdx.x >> 6, l = threadIdx.x & 63;
    const int lhi = l >> 4, llo = l & 15;

    __shared__ float lds[4][32][33];

    f32x4 acc[2][2];
#pragma unroll
    for (int i = 0; i < 2; ++i)
#pragma unroll
        for (int j = 0; j < 2; ++j) acc[i][j] = (f32x4){0.f, 0.f, 0.f, 0.f};

    const int kw = ks * 1024 + wv * 256 + lhi * 8;
    const ushort* a0p = actb + (size_t)(bt + llo)      * K + kw;
    const ushort* a1p = actb + (size_t)(bt + llo + 16) * K + kw;
    const ushort* b0p = wsg  + (size_t)(ct + llo)      * K + kw;
    const ushort* b1p = wsg  + (size_t)(ct + llo + 16) * K + kw;

#pragma unroll
    for (int s = 0; s < 8; ++s) {
        const int off = s * 32;
        const short8 a0 = *(const short8*)(a0p + off);
        const short8 a1 = *(const short8*)(a1p + off);
        const short8 b0 = *(const short8*)(b0p + off);
        const short8 b1 = *(const short8*)(b1p + off);
        acc[0][0] = __builtin_amdgcn_mfma_f32_16x16x32_bf16(a0, b0, acc[0][0], 0, 0, 0);
        acc[0][1] = __builtin_amdgcn_mfma_f32_16x16x32_bf16(a0, b1, acc[0][1], 0, 0, 0);
        acc[1][0] = __builtin_amdgcn_mfma_f32_16x16x32_bf16(a1, b0, acc[1][0], 0, 0, 0);
        acc[1][1] = __builtin_amdgcn_mfma_f32_16x16x32_bf16(a1, b1, acc[1][1], 0, 0, 0);
    }

#pragma unroll
    for (int i = 0; i < 2; ++i)
#pragma unroll
        for (int jj = 0; jj < 2; ++jj)
#pragma unroll
            for (int j = 0; j < 4; ++j)
                lds[wv][i * 16 + lhi * 4 + j][jj * 16 + llo] = acc[i][jj][j];
    __syncthreads();

    float* pb = partials + (size_t)ks * 16384;
#pragma unroll
    for (int u = 0; u < 4; ++u) {
        int idx = threadIdx.x + u * 256;     // 0..1023
        int m = idx >> 5, n = idx & 31;
        float v = lds[0][m][n] + lds[1][m][n] + lds[2][m][n] + lds[3][m][n];
        pb[(bt + m) * 128 + ct + n] = v;
    }
}

// ---------------- FC1 stage B: reduce 49 partials + bias + relu -----------------
__global__ void fc1_stageB(const float* __restrict__ partials,
                           const float* __restrict__ bf,
                           float* __restrict__ f1) {
    const int o = blockIdx.x * 256 + threadIdx.x;  // 0..16383
    float acc = 0.f;
    for (int ks = 0; ks < 49; ++ks) acc += partials[(size_t)ks * 16384 + o];
    f1[o] = fmaxf(acc + bf[o & 127], 0.f);
}

// ---------------- FC2 ------------------------------------------------------------
__global__ void fc2_kernel(const float* __restrict__ act,
                           const float* __restrict__ wf,
                           const float* __restrict__ bf,
                           float* __restrict__ out) {
    const int o = blockIdx.x * 256 + threadIdx.x;
    if (o >= 128 * 1000) return;
    const int b = o / 1000, co = o % 1000;
    const float* a  = act + b * 128;
    const float* wr = wf + co * 128;
    float acc = 0.f;
#pragma unroll 8
    for (int k = 0; k < 128; ++k)
        acc = fmaf(a[k], sgn(wr[k]), acc);
    out[o] = acc + bf[co];
}

extern "C" void kernel_launch(void* const* d_in, const int* in_sizes, int n_in,
                              void* d_out, int out_size, void* d_ws, size_t ws_size,
                              hipStream_t stream) {
    const float* x   = (const float*)d_in[0];
    const float* w1  = (const float*)d_in[1];
    const float* b1  = (const float*)d_in[2];
    const float* w2  = (const float*)d_in[3];
    const float* b2  = (const float*)d_in[4];
    const float* w3  = (const float*)d_in[5];
    const float* b3  = (const float*)d_in[6];
    const float* wf1 = (const float*)d_in[7];
    const float* bf1 = (const float*)d_in[8];
    const float* wf2 = (const float*)d_in[9];
    const float* bf2 = (const float*)d_in[10];

    // ws layout (x4 eliminated; offsets kept from round 9, all within 133.1 MB):
    //   h1p bf16 [128,114,114,16] @ 0            (53,231,616)
    //   h3b  bf16 [128][50176]    @ 53,231,616   (12,845,056)  NHWC-permuted K
    //   wsg1 bf16 [128][50176]    @ 66,076,672   (12,845,056)  same K-perm
    //   pa   fp32 [49][16384]     @ 78,921,728   ( 3,211,264)
    //   f1   fp32 [128,128]       @ 82,132,992   (    65,536)
    //   h2p bf16 [128,58,58,32]   @ 105,507,840  (27,557,888)
    //   wf1frag @ 133,065,728 (2,048); wf2frag @ 133,067,776 (10,240);
    //   wf3frag @ 133,078,016 (36,864)
    char* ws = (char*)d_ws;
    ushort* h1p  = (ushort*)ws;
    ushort* h3b  = (ushort*)(ws + 53231616u);
    ushort* wsg1 = (ushort*)(ws + 66076672u);
    float*  pa   = (float*) (ws + 78921728u);
    float*  f1   = (float*) (ws + 82132992u);
    ushort* h2p  = (ushort*)(ws + 105507840u);
    ushort* wf1frag = (ushort*)(ws + 133065728u);
    ushort* wf2frag = (ushort*)(ws + 133067776u);
    ushort* wf3frag = (ushort*)(ws + 133078016u);

    pad_zero<<<7265, 256, 0, stream>>>(h1p, h2p);
    wfrag_prep<<<96, 256, 0, stream>>>(w2, w3, w1, wf2frag, wf3frag, wf1frag);
    wf1_prep_t<<<dim3(7, 128), 256, 0, stream>>>(wf1, wsg1);
    conv1_fused<<<dim3(112, 1, 128), 256, 0, stream>>>(x, wf1frag, b1, h1p);
    conv2_mfma<<<dim3(28, 1, 128), 256, 0, stream>>>(h1p, wf2frag, b2, h2p);
    conv3_mfma<<<dim3(7, 1, 128), 256, 0, stream>>>(h2p, wf3frag, b3, h3b);
    fc1_mfmaA<<<dim3(4, 4, 49), 256, 0, stream>>>(h3b, wsg1, pa);
    fc1_stageB<<<64, 256, 0, stream>>>(pa, bf1, f1);
    fc2_kernel<<<500, 256, 0, stream>>>(f1, wf2, bf2, (float*)d_out);
}